// Round 1
// baseline (1429.339 us; speedup 1.0000x reference)
//
#include <hip/hip_runtime.h>
#include <hip/hip_bf16.h>

// Problem dims
#define BB 16
#define SS 512
#define IN_ 128
#define DD 512
#define HH 512
#define DA 30
#define RR 10
#define G3 1536   // 3*H

// ---- ws layout (bytes) ----
constexpr size_t OFF_H    = 0;                        // tagged h ring u32[2][16][512]: 65,536
constexpr size_t OFF_DF   = 131072;                   // dtype flag: 256
constexpr size_t OFF_CX   = OFF_DF   + 256;           // canonical fp32 inputs
constexpr size_t OFF_CW0  = OFF_CX   + 4194304;
constexpr size_t OFF_CB0  = OFF_CW0  + 262144;
constexpr size_t OFF_CW1  = OFF_CB0  + 2048;
constexpr size_t OFF_CB1  = OFF_CW1  + 61440;
constexpr size_t OFF_CW2  = OFF_CB1  + 256;
constexpr size_t OFF_CB2  = OFF_CW2  + 2048;
constexpr size_t OFF_CWIH = OFF_CB2  + 256;
constexpr size_t OFF_CWHH = OFF_CWIH + 3145728;
constexpr size_t OFF_CBI  = OFF_CWHH + 3145728;
constexpr size_t OFF_CBH  = OFF_CBI  + 6144;
constexpr size_t OFF_WT   = OFF_CBH  + 6144;          // W_hh^T bf16 [1536][512]
constexpr size_t OFF_WIHT = OFF_WT   + 1572864;       // W_ih^T bf16 [1536][512]
constexpr size_t OFF_W0T  = OFF_WIHT + 1572864;       // W0^T bf16 [512][128]
constexpr size_t OFF_MM   = OFF_W0T  + 131072;        // M bf16 [8192][512]
constexpr size_t OFF_BIG  = OFF_MM   + 8388608;
constexpr size_t OFF_M    = OFF_BIG;                  // m bf16 [8192][512]
constexpr size_t OFF_E    = OFF_BIG  + 8388608;       // e f32 [8192][10]
constexpr size_t OFF_INV  = OFF_E    + 327680;        // inv f32
constexpr size_t OFF_GI   = OFF_BIG;                  // gi aliases m/e/inv (dead after k_attn)
constexpr size_t NEED_GI32 = OFF_BIG + 50331648;      // gi fp32 path total

typedef __attribute__((ext_vector_type(8))) short bf16x8;
typedef __attribute__((ext_vector_type(4))) float f32x4;

__device__ __forceinline__ float bflo(unsigned int u) { return __uint_as_float(u << 16); }
__device__ __forceinline__ float bfhi(unsigned int u) { return __uint_as_float(u & 0xffff0000u); }
__device__ __forceinline__ float bf1(unsigned short u) { return __uint_as_float(((unsigned int)u) << 16); }
__device__ __forceinline__ unsigned short f2b(float f) {
  __hip_bfloat16 h = __float2bfloat16(f);
  return *(unsigned short*)&h;
}

__device__ __forceinline__ float ldgi(const float* p) { return *p; }
__device__ __forceinline__ float ldgi(const __hip_bfloat16* p) { return __bfloat162float(*p); }
__device__ __forceinline__ void stgi(float* p, float v) { *p = v; }
__device__ __forceinline__ void stgi(__hip_bfloat16* p, float v) { *p = __float2bfloat16(v); }

// ---------------- K0a: detect input dtype + zero the h ring ----------------
__global__ __launch_bounds__(256) void k_detect(const unsigned short* __restrict__ xs,
                                                int* __restrict__ dflag,
                                                uint4* __restrict__ hz) {
  const int tid = threadIdx.x;
  // zero tagged h ring: 65,536 B = 4096 uint4 (bits 0 == h=0.0 with tag 0)
  const uint4 z = {0u, 0u, 0u, 0u};
  #pragma unroll
  for (int i = 0; i < 16; i++) hz[tid + i * 256] = z;
  int bad = 0;
  for (int i = tid; i < 8192; i += 256) {
    const float v = bf1(xs[i]);
    if (!(fabsf(v) < 1.0e3f)) bad++;   // NaN also counts
  }
  __shared__ int s;
  if (tid == 0) s = 0;
  __syncthreads();
  atomicAdd(&s, bad);
  __syncthreads();
  if (tid == 0) dflag[0] = (s > 16) ? 1 : 0;   // 1 = fp32 buffers, 0 = bf16 buffers
}

// ---------------- K0b: canonicalize all inputs to fp32 ----------------
struct CvtArgs { const void* src[11]; float* dst[11]; int n[11]; };
__global__ __launch_bounds__(256) void k_cvt(CvtArgs a, const int* __restrict__ dflag) {
  const int ai = blockIdx.y;
  const int n = a.n[ai];
  const int stride = gridDim.x * blockDim.x;
  const int f32 = dflag[0];
  float* dst = a.dst[ai];
  if (f32) {
    const float* src = (const float*)a.src[ai];
    for (int i = blockIdx.x * blockDim.x + threadIdx.x; i < n; i += stride) dst[i] = src[i];
  } else {
    const unsigned short* src = (const unsigned short*)a.src[ai];
    for (int i = blockIdx.x * blockDim.x + threadIdx.x; i < n; i += stride) dst[i] = bf1(src[i]);
  }
}

// ---------------- K1: fused transpose of W_hh, W_ih (512x1536) and W0 (128x512) ------
__global__ __launch_bounds__(1024) void k_transpose3(const float* __restrict__ Whh,
    const float* __restrict__ Wih, const float* __restrict__ W0,
    __hip_bfloat16* __restrict__ WhhT, __hip_bfloat16* __restrict__ WihT,
    __hip_bfloat16* __restrict__ W0T) {
  __shared__ float tile[32][33];
  int id = blockIdx.x;
  const float* W; __hip_bfloat16* WT; int R, C, tx, ty;
  if (id < 768)       { W = Whh; WT = WhhT; R = DD;  C = G3; tx = id % 48; ty = id / 48; }
  else if (id < 1536) { id -= 768;  W = Wih; WT = WihT; R = DD;  C = G3; tx = id % 48; ty = id / 48; }
  else                { id -= 1536; W = W0;  WT = W0T;  R = IN_; C = DD; tx = id % 16; ty = id / 16; }
  const int c0 = tx * 32, k0 = ty * 32;
  tile[threadIdx.y][threadIdx.x] = W[(k0 + threadIdx.y) * C + c0 + threadIdx.x];
  __syncthreads();
  WT[(c0 + threadIdx.y) * R + k0 + threadIdx.x] = __float2bfloat16(tile[threadIdx.x][threadIdx.y]);
}

// ---------------- K5: unified MFMA GEMM: C[M][N] = A[M][KD] @ Bt[N][KD]^T + bias ------
// Tile 128x128, 4 waves (2x2 of 64x64), BK=32. A staged fp32->bf16 or bf16 direct.
// C/D frag: col=lane&15, row=quad*4+reg (m89-verified).
template<typename AT, typename GT, int KD, bool RELU>
__global__ __launch_bounds__(256) void k_gemm(const AT* __restrict__ A,
    const __hip_bfloat16* __restrict__ Bt, const float* __restrict__ bias,
    GT* __restrict__ C, int ldc) {
  __shared__ short As[128 * 40];   // 128 rows x 32 k, stride 40 (bank de-phase)
  __shared__ short Bs[128 * 40];
  const int tid = threadIdx.x;
  const int bn = blockIdx.x * 128, bm = blockIdx.y * 128;
  const int lane = tid & 63, w = tid >> 6;
  const int wm = (w >> 1) * 64, wn = (w & 1) * 64;
  const int l15 = lane & 15, quad = lane >> 4;
  const int srow = tid >> 1, shalf = tid & 1;    // staging: row, 16-elem half of 32-chunk
  f32x4 acc[4][4];
  #pragma unroll
  for (int i = 0; i < 4; i++)
    #pragma unroll
    for (int j = 0; j < 4; j++) acc[i][j] = (f32x4){0.f, 0.f, 0.f, 0.f};
  const uint4* Bg = (const uint4*)(Bt + (size_t)(bn + srow) * KD);
  short* Asd = &As[srow * 40 + shalf * 16];
  short* Bsd = &Bs[srow * 40 + shalf * 16];
  #pragma unroll 2
  for (int kc = 0; kc < KD / 32; kc++) {
    if constexpr (sizeof(AT) == 4) {   // fp32 A: 16 floats -> 16 bf16
      const float4* Agf = (const float4*)(A + (size_t)(bm + srow) * KD) + kc * 8 + shalf * 4;
      const float4 f0 = Agf[0], f1 = Agf[1], f2 = Agf[2], f3 = Agf[3];
      unsigned short t16[16] = {
        f2b(f0.x), f2b(f0.y), f2b(f0.z), f2b(f0.w),
        f2b(f1.x), f2b(f1.y), f2b(f1.z), f2b(f1.w),
        f2b(f2.x), f2b(f2.y), f2b(f2.z), f2b(f2.w),
        f2b(f3.x), f2b(f3.y), f2b(f3.z), f2b(f3.w)};
      *(uint4*)&Asd[0] = *(uint4*)&t16[0];
      *(uint4*)&Asd[8] = *(uint4*)&t16[8];
    } else {                            // bf16 A
      const uint4* Ag = (const uint4*)(A + (size_t)(bm + srow) * KD);
      const uint4 a0 = Ag[kc * 4 + shalf * 2], a1 = Ag[kc * 4 + shalf * 2 + 1];
      *(uint4*)&Asd[0] = a0; *(uint4*)&Asd[8] = a1;
    }
    const uint4 b0 = Bg[kc * 4 + shalf * 2], b1 = Bg[kc * 4 + shalf * 2 + 1];
    *(uint4*)&Bsd[0] = b0; *(uint4*)&Bsd[8] = b1;
    __syncthreads();
    bf16x8 af[4], bf[4];
    #pragma unroll
    for (int tt = 0; tt < 4; tt++) {
      af[tt] = *(const bf16x8*)&As[(wm + tt * 16 + l15) * 40 + quad * 8];
      bf[tt] = *(const bf16x8*)&Bs[(wn + tt * 16 + l15) * 40 + quad * 8];
    }
    #pragma unroll
    for (int tm = 0; tm < 4; tm++)
      #pragma unroll
      for (int tn = 0; tn < 4; tn++)
        acc[tm][tn] = __builtin_amdgcn_mfma_f32_16x16x32_bf16(af[tm], bf[tn], acc[tm][tn], 0, 0, 0);
    __syncthreads();
  }
  #pragma unroll
  for (int tn = 0; tn < 4; tn++) {
    const int col = bn + wn + tn * 16 + l15;
    const float bv = bias[col];
    #pragma unroll
    for (int tm = 0; tm < 4; tm++) {
      const int row = bm + wm + tm * 16 + quad * 4;
      #pragma unroll
      for (int i = 0; i < 4; i++) {
        float v = acc[tm][tn][i] + bv;
        if constexpr (RELU) v = fmaxf(v, 0.f);
        stgi(C + (size_t)(row + i) * ldc + col, v);
      }
    }
  }
}

// ---------------- K2b: scores per row: e = exp(tanh(m@W1+b1)@W2+b2) ----------------
__global__ __launch_bounds__(256) void k_scores(const __hip_bfloat16* __restrict__ m,
    const float* __restrict__ W1, const float* __restrict__ b1,
    const float* __restrict__ W2, const float* __restrict__ b2,
    float* __restrict__ e) {
  const int row = blockIdx.x;        // b*512+s
  const int tid = threadIdx.x;       // 256
  __shared__ float ms[DD];
  __shared__ float as[DA];
  __shared__ float part[8][32];
  {
    const unsigned int mm = ((const unsigned int*)(m + (size_t)row * DD))[tid];
    ms[2 * tid] = bflo(mm); ms[2 * tid + 1] = bfhi(mm);
  }
  __syncthreads();
  const int a2 = tid & 31, seg = tid >> 5;
  float p = 0.f;
  if (a2 < DA) {
    const int kb = seg * 64;
    #pragma unroll 8
    for (int k = 0; k < 64; k++) p = fmaf(ms[kb + k], W1[(kb + k) * DA + a2], p);
  }
  part[seg][a2] = p;
  __syncthreads();
  if (tid < DA) {
    float a = b1[tid];
    #pragma unroll
    for (int s = 0; s < 8; s++) a += part[s][tid];
    as[tid] = tanhf(a);
  }
  __syncthreads();
  if (tid < RR) {
    float s = b2[tid];
    #pragma unroll
    for (int j = 0; j < DA; j++) s = fmaf(as[j], W2[j * RR + tid], s);
    e[row * RR + tid] = __expf(s);
  }
}

// ---------------- K3: per-(b,r) prefix scan -> inv[b,k,r] = 1/cumsum_k e ----------------
__global__ __launch_bounds__(64) void k_scan(const float* __restrict__ e, float* __restrict__ inv) {
  const int b = blockIdx.x / RR, r = blockIdx.x % RR;
  const int lane = threadIdx.x;  // 64
  float v[8];
  float sum = 0.f;
  #pragma unroll
  for (int i = 0; i < 8; i++) { v[i] = e[(b * SS + lane * 8 + i) * RR + r]; sum += v[i]; }
  float inc = sum;
  #pragma unroll
  for (int off = 1; off < 64; off <<= 1) {
    float n = __shfl_up(inc, off);
    if (lane >= off) inc += n;
  }
  float c = inc - sum;  // exclusive prefix
  #pragma unroll
  for (int i = 0; i < 8; i++) { c += v[i]; inv[(b * SS + lane * 8 + i) * RR + r] = 1.0f / c; }
}

// ---------------- K4: attention as streaming scan: M[t,d] = (1/R) sum_r cums(e*m)*inv ----
__global__ __launch_bounds__(128) void k_attn(const __hip_bfloat16* __restrict__ m,
    const float* __restrict__ e, const float* __restrict__ inv, __hip_bfloat16* __restrict__ M) {
  const int b = blockIdx.y;
  const int d = blockIdx.x * 128 + threadIdx.x;
  __shared__ float es[SS * RR];
  __shared__ float is[SS * RR];
  for (int i = threadIdx.x; i < SS * RR; i += 128) {
    es[i] = e[b * SS * RR + i];
    is[i] = inv[b * SS * RR + i];
  }
  __syncthreads();
  float num[RR];
  #pragma unroll
  for (int r = 0; r < RR; r++) num[r] = 0.f;
  const __hip_bfloat16* mb = m + (size_t)b * SS * DD + d;
  __hip_bfloat16* Mb = M + (size_t)b * SS * DD + d;
  #pragma unroll 4
  for (int k = 0; k < SS; k++) {
    const float mv = __bfloat162float(mb[(size_t)k * DD]);
    float acc = 0.f;
    #pragma unroll
    for (int r = 0; r < RR; r++) {
      num[r] = fmaf(es[k * RR + r], mv, num[r]);
      acc = fmaf(num[r], is[k * RR + r], acc);
    }
    Mb[(size_t)k * DD] = __float2bfloat16(acc * (1.0f / RR));
  }
}

// ---------------- K6 v5: MFMA-batched persistent GRU — 16 blocks TOTAL ----------------
// All 16 batches share the MFMA M-dim: gh(16x96-slice) = H(16x512) @ W_hh-slice per step.
// 16 blocks x 512 threads (1/CU). Block g owns j-slice [g*32, g*32+32) for ALL batches.
// W_hh^T slice (96 rows x 512 K, bf16) resident in VGPRs of 3 MFMA waves (2 N-tiles each,
// 128 VGPRs). h exchange: tagged u32 ring [2][16][512] (2-bit step tag in fp32 LSBs),
// agent-scope stores, sc0 sc1 poll (proven scheme from v4, now 4 uint4/thread).
// h_prev is a per-thread fp32 REGISTER (one thread per (b,j)) -> pristine recurrence path;
// bf16(h) only enters the gh product (same error class as bf16 W).
// A-LDS layout: bf16, byte = ks*1040 + b*64 + (k%32)*2 (ks-stride 1040 de-phases banks:
// stage-writes 2-way, frag-reads volume-limited 1KB contiguous). gi double-buffered in regs.
// 2 barriers/step. Per-step: poll -> stage -> bar -> 48 MFMA (3 waves) -> bar -> gates.
template<typename GT>
__global__ __launch_bounds__(512, 2) void k_gru(const __hip_bfloat16* __restrict__ WT,
    const GT* __restrict__ gi, const float* __restrict__ bh,
    unsigned int* __restrict__ hslots, void* __restrict__ outv,
    const int* __restrict__ dflag) {
  const int g = blockIdx.x;          // j-slice
  const int tid = threadIdx.x;       // 512
  const int f32o = dflag[0];
  const int lane = tid & 63;
  const int l15 = lane & 15, quad = lane >> 4;
  const int w = tid >> 6;            // wave 0..7; waves 0..2 do MFMA (wave == gate)
  __shared__ __align__(16) short Ah[16 * 520];   // [ks] stride 520 shorts, [b] stride 32
  __shared__ float ghs[96 * 20];                 // [n 0..95][b] padded to 20
  // ---- W_hh^T slice resident in registers (MFMA waves only) ----
  bf16x8 br0[16], br1[16];
  if (w < 3) {
    const __hip_bfloat16* wp0 = WT + (size_t)(w * 512 + g * 32 + l15) * HH + quad * 8;
    #pragma unroll
    for (int ks = 0; ks < 16; ks++) {
      br0[ks] = *(const bf16x8*)(wp0 + ks * 32);            // rows jj 0..15 of gate w
      br1[ks] = *(const bf16x8*)(wp0 + 16 * HH + ks * 32);  // rows jj 16..31
    }
  }
  // ---- gates identity: one thread per (batch, jj) ----
  const int gb = tid >> 5;           // batch 0..15
  const int jj = tid & 31;
  const int jg = g * 32 + jj;
  const float bhr = bh[jg], bhz = bh[512 + jg], bhn = bh[1024 + jg];
  const GT* gib = gi + (size_t)gb * SS * G3;
  float gr = ldgi(gib + jg), gz = ldgi(gib + 512 + jg), gn = ldgi(gib + 1024 + jg);
  float hreg = 0.f;                  // fp32 h_prev lives here across all 512 steps
  // ---- poll identity: thread covers 64B = 16 h values of batch (tid>>5) ----
  const int ks0 = (tid & 31) >> 1;
  const int jmb = 16 * (tid & 1);
  unsigned int* s0 = hslots;                 // [16][512] u32
  unsigned int* s1 = hslots + BB * HH;

  for (int t = 0; t < SS; t++) {
    unsigned int* cur = (t & 1) ? s1 : s0;
    unsigned int* nxt = (t & 1) ? s0 : s1;
    // ---- poll h_t (self-tagged dwords, tag == t&3) + stage bf16 to LDS ----
    {
      const uint4* src = (const uint4*)cur + tid * 4;
      const unsigned want = (unsigned)t & 3u;
      uint4 v0, v1, v2, v3;
      for (;;) {
        asm volatile(
            "global_load_dwordx4 %0, %4, off sc0 sc1\n\t"
            "global_load_dwordx4 %1, %4, off offset:16 sc0 sc1\n\t"
            "global_load_dwordx4 %2, %4, off offset:32 sc0 sc1\n\t"
            "global_load_dwordx4 %3, %4, off offset:48 sc0 sc1\n\t"
            "s_waitcnt vmcnt(0)"
            : "=v"(v0), "=v"(v1), "=v"(v2), "=v"(v3)
            : "v"(src) : "memory");
        const unsigned bad =
            ((v0.x ^ want) | (v0.y ^ want) | (v0.z ^ want) | (v0.w ^ want) |
             (v1.x ^ want) | (v1.y ^ want) | (v1.z ^ want) | (v1.w ^ want) |
             (v2.x ^ want) | (v2.y ^ want) | (v2.z ^ want) | (v2.w ^ want) |
             (v3.x ^ want) | (v3.y ^ want) | (v3.z ^ want) | (v3.w ^ want)) & 3u;
        if (bad == 0) break;
      }
      short* Arow = &Ah[ks0 * 520 + gb * 32];
      auto st8 = [&](const uint4& v, int jm) {
        const unsigned lo = (unsigned)f2b(__uint_as_float(v.x)) |
                            ((unsigned)f2b(__uint_as_float(v.y)) << 16);
        const unsigned hi = (unsigned)f2b(__uint_as_float(v.z)) |
                            ((unsigned)f2b(__uint_as_float(v.w)) << 16);
        *(unsigned long long*)&Arow[jm] =
            (unsigned long long)lo | ((unsigned long long)hi << 32);
      };
      st8(v0, jmb); st8(v1, jmb + 4); st8(v2, jmb + 8); st8(v3, jmb + 12);
    }
    __syncthreads();                                    // #1 (stage -> MFMA; ghs WAR)
    // prefetch gi for t+1 (latency hidden under MFMA + gates)
    float pr = gr, pz = gz, pn = gn;
    if (t + 1 < SS) {
      const GT* gp = gib + (size_t)(t + 1) * G3;
      pr = ldgi(gp + jg); pz = ldgi(gp + 512 + jg); pn = ldgi(gp + 1024 + jg);
    }
    // ---- MFMA: D[b][n] = H(16x512) @ Wslice; A row=b by l15, D row=b by quad*4+i ----
    if (w < 3) {
      f32x4 a0 = {0.f, 0.f, 0.f, 0.f}, a1 = {0.f, 0.f, 0.f, 0.f};
      #pragma unroll
      for (int ks = 0; ks < 16; ks++) {
        const bf16x8 af = *(const bf16x8*)&Ah[ks * 520 + l15 * 32 + quad * 8];
        a0 = __builtin_amdgcn_mfma_f32_16x16x32_bf16(af, br0[ks], a0, 0, 0, 0);
        a1 = __builtin_amdgcn_mfma_f32_16x16x32_bf16(af, br1[ks], a1, 0, 0, 0);
      }
      const int n0 = w * 32 + l15;
      #pragma unroll
      for (int i = 0; i < 4; i++) {
        ghs[n0 * 20 + quad * 4 + i] = a0[i];
        ghs[(n0 + 16) * 20 + quad * 4 + i] = a1[i];
      }
    }
    __syncthreads();                                    // #2 (ghs -> gates)
    // ---- gates: every thread owns one (b, jj); h_prev in register ----
    {
      const float ghr = ghs[jj * 20 + gb] + bhr;
      const float ghz = ghs[(32 + jj) * 20 + gb] + bhz;
      const float ghn = ghs[(64 + jj) * 20 + gb] + bhn;
      const float r = 1.f / (1.f + __expf(-(gr + ghr)));
      const float z = 1.f / (1.f + __expf(-(gz + ghz)));
      const float nx = gn + r * ghn;
      const float n = 1.f - 2.f / (__expf(2.f * nx) + 1.f);   // tanh
      const float hnew = n + z * (hreg - n);
      hreg = hnew;
      const unsigned pk = (__float_as_uint(hnew) & ~3u) | (((unsigned)(t + 1)) & 3u);
      __hip_atomic_store(nxt + gb * HH + jg, pk, __ATOMIC_RELAXED, __HIP_MEMORY_SCOPE_AGENT);
      const size_t oi = ((size_t)gb * SS + t) * HH + jg;
      if (f32o) ((float*)outv)[oi] = hnew;
      else ((__hip_bfloat16*)outv)[oi] = __float2bfloat16(hnew);
    }
    gr = pr; gz = pz; gn = pn;
  }
}

extern "C" void kernel_launch(void* const* d_in, const int* in_sizes, int n_in,
                              void* d_out, int out_size, void* d_ws, size_t ws_size,
                              hipStream_t stream) {
  char* wsb = (char*)d_ws;
  unsigned int* hslots = (unsigned int*)(wsb + OFF_H);
  int* dflag  = (int*)(wsb + OFF_DF);
  float* cx   = (float*)(wsb + OFF_CX);
  float* cW0  = (float*)(wsb + OFF_CW0);
  float* cb0  = (float*)(wsb + OFF_CB0);
  float* cW1  = (float*)(wsb + OFF_CW1);
  float* cb1  = (float*)(wsb + OFF_CB1);
  float* cW2  = (float*)(wsb + OFF_CW2);
  float* cb2  = (float*)(wsb + OFF_CB2);
  float* cWih = (float*)(wsb + OFF_CWIH);
  float* cWhh = (float*)(wsb + OFF_CWHH);
  float* cbi  = (float*)(wsb + OFF_CBI);
  float* cbh  = (float*)(wsb + OFF_CBH);
  __hip_bfloat16* WT   = (__hip_bfloat16*)(wsb + OFF_WT);
  __hip_bfloat16* WihT = (__hip_bfloat16*)(wsb + OFF_WIHT);
  __hip_bfloat16* W0T  = (__hip_bfloat16*)(wsb + OFF_W0T);
  __hip_bfloat16* Mm   = (__hip_bfloat16*)(wsb + OFF_MM);
  __hip_bfloat16* m    = (__hip_bfloat16*)(wsb + OFF_M);
  float* e   = (float*)(wsb + OFF_E);
  float* inv = (float*)(wsb + OFF_INV);
  void* gip  = (void*)(wsb + OFF_GI);
  const bool gi32 = (ws_size >= NEED_GI32);   // constant across calls -> same work every call

  // k_detect zeroes the h ring (ws is poisoned 0xAA before every call) and sets dflag
  k_detect<<<1, 256, 0, stream>>>((const unsigned short*)d_in[0], dflag, (uint4*)hslots);

  CvtArgs ca;
  float* dsts[11] = {cx, cW0, cb0, cW1, cb1, cW2, cb2, cWih, cWhh, cbi, cbh};
  const int ns[11] = {BB * SS * IN_, IN_ * DD, DD, DD * DA, DA, DA * RR, RR,
                      DD * G3, HH * G3, G3, G3};
  for (int i = 0; i < 11; i++) { ca.src[i] = d_in[i]; ca.dst[i] = dsts[i]; ca.n[i] = ns[i]; }
  k_cvt<<<dim3(128, 11), 256, 0, stream>>>(ca, dflag);

  k_transpose3<<<1600, dim3(32, 32), 0, stream>>>(cWhh, cWih, cW0, WT, WihT, W0T);
  // m = relu(x @ W0 + b0) via MFMA (fp32 A staged to bf16)
  k_gemm<float, __hip_bfloat16, IN_, true>
      <<<dim3(DD / 128, (BB * SS) / 128), 256, 0, stream>>>(cx, W0T, cb0, m, DD);
  k_scores<<<BB * SS, 256, 0, stream>>>(m, cW1, cb1, cW2, cb2, e);
  k_scan<<<BB * RR, 64, 0, stream>>>(e, inv);
  k_attn<<<dim3(4, BB), 128, 0, stream>>>(m, e, inv, Mm);
  if (gi32) {
    k_gemm<__hip_bfloat16, float, DD, false>
        <<<dim3(G3 / 128, (BB * SS) / 128), 256, 0, stream>>>(Mm, WihT, cbi, (float*)gip, G3);
    k_gru<float><<<16, 512, 0, stream>>>(WT, (const float*)gip, cbh, hslots, d_out, dflag);
  } else {
    k_gemm<__hip_bfloat16, __hip_bfloat16, DD, false>
        <<<dim3(G3 / 128, (BB * SS) / 128), 256, 0, stream>>>(Mm, WihT, cbi,
                                                              (__hip_bfloat16*)gip, G3);
    k_gru<__hip_bfloat16><<<16, 512, 0, stream>>>(WT, (const __hip_bfloat16*)gip, cbh,
                                                  hslots, d_out, dflag);
  }
}

// Round 4
// 1320.703 us; speedup vs baseline: 1.0823x; 1.0823x over previous
//
#include <hip/hip_runtime.h>
#include <hip/hip_bf16.h>

// Problem dims
#define BB 16
#define SS 512
#define IN_ 128
#define DD 512
#define HH 512
#define DA 30
#define RR 10
#define G3 1536   // 3*H

// ---- ws layout (bytes) ----
// h exchange ring: PAIRS (h_bits, salt+t) u32[2][16][512][2] = 131,072 B (exact fit)
constexpr size_t OFF_H    = 0;
constexpr size_t OFF_DF   = 131072;                   // dflag[0]=dtype, dflag[1]=salt: 256
constexpr size_t OFF_CX   = OFF_DF   + 256;           // canonical fp32 inputs
constexpr size_t OFF_CW0  = OFF_CX   + 4194304;
constexpr size_t OFF_CB0  = OFF_CW0  + 262144;
constexpr size_t OFF_CW1  = OFF_CB0  + 2048;
constexpr size_t OFF_CB1  = OFF_CW1  + 61440;
constexpr size_t OFF_CW2  = OFF_CB1  + 256;
constexpr size_t OFF_CB2  = OFF_CW2  + 2048;
constexpr size_t OFF_CWIH = OFF_CB2  + 256;
constexpr size_t OFF_CWHH = OFF_CWIH + 3145728;
constexpr size_t OFF_CBI  = OFF_CWHH + 3145728;
constexpr size_t OFF_CBH  = OFF_CBI  + 6144;
constexpr size_t OFF_WT   = OFF_CBH  + 6144;          // W_hh^T bf16 [1536][512]
constexpr size_t OFF_WIHT = OFF_WT   + 1572864;       // W_ih^T bf16 [1536][512]
constexpr size_t OFF_W0T  = OFF_WIHT + 1572864;       // W0^T bf16 [512][128]; dead after
                                                      // k_gemm #1 -> reused as pub[] by k_gru
constexpr size_t OFF_MM   = OFF_W0T  + 131072;        // M bf16 [8192][512]
constexpr size_t OFF_BIG  = OFF_MM   + 8388608;
constexpr size_t OFF_M    = OFF_BIG;                  // m bf16 [8192][512]
constexpr size_t OFF_E    = OFF_BIG  + 8388608;       // e f32 [8192][10]
constexpr size_t OFF_INV  = OFF_E    + 327680;        // inv f32
constexpr size_t OFF_GI   = OFF_BIG;                  // gi aliases m/e/inv (dead after k_attn)
constexpr size_t NEED_GI32 = OFF_BIG + 50331648;      // gi fp32 path total

typedef __attribute__((ext_vector_type(8))) short bf16x8;
typedef __attribute__((ext_vector_type(4))) float f32x4;

__device__ __forceinline__ float bflo(unsigned int u) { return __uint_as_float(u << 16); }
__device__ __forceinline__ float bfhi(unsigned int u) { return __uint_as_float(u & 0xffff0000u); }
__device__ __forceinline__ float bf1(unsigned short u) { return __uint_as_float(((unsigned int)u) << 16); }
__device__ __forceinline__ unsigned short f2b(float f) {
  __hip_bfloat16 h = __float2bfloat16(f);
  return *(unsigned short*)&h;
}

__device__ __forceinline__ float ldgi(const float* p) { return *p; }
__device__ __forceinline__ float ldgi(const __hip_bfloat16* p) { return __bfloat162float(*p); }
__device__ __forceinline__ void stgi(float* p, float v) { *p = v; }
__device__ __forceinline__ void stgi(__hip_bfloat16* p, float v) { *p = __float2bfloat16(v); }

// ---------------- K0a: detect input dtype + seed the pair ring with (0, salt) ----------
// salt = per-dispatch value from s_memrealtime (device-side: graph replays re-salt).
// Seed (h=0, word=salt) is EXACTLY the t=0 state -> consumers accept h_0=0 instantly.
// No future want (salt+t, t>=1) ever matches a seed/stale/poisoned word (exact match).
__global__ __launch_bounds__(256) void k_detect(const unsigned short* __restrict__ xs,
                                                int* __restrict__ dflag,
                                                uint4* __restrict__ hz) {
  const int tid = threadIdx.x;
  __shared__ unsigned ssalt;
  if (tid == 0) {
    const unsigned long long rt = __builtin_amdgcn_s_memrealtime();
    // top nibble forced to 0x1: never collides with 0xAAAAAAAA poison or bf16 weight words
    ssalt = ((unsigned)(rt ^ (rt >> 32)) & 0x0FFFFFFFu) | 0x10000000u;
  }
  __syncthreads();
  const unsigned salt = ssalt;
  const uint4 seed = {0u, salt, 0u, salt};   // two (h=0, word=salt) pairs
  #pragma unroll
  for (int i = 0; i < 32; i++) hz[tid + i * 256] = seed;   // 8192 uint4 = 131,072 B
  int bad = 0;
  for (int i = tid; i < 8192; i += 256) {
    const float v = bf1(xs[i]);
    if (!(fabsf(v) < 1.0e3f)) bad++;   // NaN also counts
  }
  __shared__ int s;
  if (tid == 0) s = 0;
  __syncthreads();
  atomicAdd(&s, bad);
  __syncthreads();
  if (tid == 0) {
    dflag[0] = (s > 16) ? 1 : 0;   // 1 = fp32 buffers, 0 = bf16 buffers
    ((unsigned*)dflag)[1] = salt;
  }
}

// ---------------- K0b: canonicalize all inputs to fp32 ----------------
struct CvtArgs { const void* src[11]; float* dst[11]; int n[11]; };
__global__ __launch_bounds__(256) void k_cvt(CvtArgs a, const int* __restrict__ dflag) {
  const int ai = blockIdx.y;
  const int n = a.n[ai];
  const int stride = gridDim.x * blockDim.x;
  const int f32 = dflag[0];
  float* dst = a.dst[ai];
  if (f32) {
    const float* src = (const float*)a.src[ai];
    for (int i = blockIdx.x * blockDim.x + threadIdx.x; i < n; i += stride) dst[i] = src[i];
  } else {
    const unsigned short* src = (const unsigned short*)a.src[ai];
    for (int i = blockIdx.x * blockDim.x + threadIdx.x; i < n; i += stride) dst[i] = bf1(src[i]);
  }
}

// ---------------- K1: fused transpose of W_hh, W_ih (512x1536) and W0 (128x512) ------
__global__ __launch_bounds__(1024) void k_transpose3(const float* __restrict__ Whh,
    const float* __restrict__ Wih, const float* __restrict__ W0,
    __hip_bfloat16* __restrict__ WhhT, __hip_bfloat16* __restrict__ WihT,
    __hip_bfloat16* __restrict__ W0T) {
  __shared__ float tile[32][33];
  int id = blockIdx.x;
  const float* W; __hip_bfloat16* WT; int R, C, tx, ty;
  if (id < 768)       { W = Whh; WT = WhhT; R = DD;  C = G3; tx = id % 48; ty = id / 48; }
  else if (id < 1536) { id -= 768;  W = Wih; WT = WihT; R = DD;  C = G3; tx = id % 48; ty = id / 48; }
  else                { id -= 1536; W = W0;  WT = W0T;  R = IN_; C = DD; tx = id % 16; ty = id / 16; }
  const int c0 = tx * 32, k0 = ty * 32;
  tile[threadIdx.y][threadIdx.x] = W[(k0 + threadIdx.y) * C + c0 + threadIdx.x];
  __syncthreads();
  WT[(c0 + threadIdx.y) * R + k0 + threadIdx.x] = __float2bfloat16(tile[threadIdx.x][threadIdx.y]);
}

// ---------------- K5: unified MFMA GEMM: C[M][N] = A[M][KD] @ Bt[N][KD]^T + bias ------
// Tile 128x128, 4 waves (2x2 of 64x64), BK=32. A staged fp32->bf16 or bf16 direct.
// C/D frag: col=lane&15, row=quad*4+reg (m89-verified).
template<typename AT, typename GT, int KD, bool RELU>
__global__ __launch_bounds__(256) void k_gemm(const AT* __restrict__ A,
    const __hip_bfloat16* __restrict__ Bt, const float* __restrict__ bias,
    GT* __restrict__ C, int ldc) {
  __shared__ short As[128 * 40];   // 128 rows x 32 k, stride 40 (bank de-phase)
  __shared__ short Bs[128 * 40];
  const int tid = threadIdx.x;
  const int bn = blockIdx.x * 128, bm = blockIdx.y * 128;
  const int lane = tid & 63, w = tid >> 6;
  const int wm = (w >> 1) * 64, wn = (w & 1) * 64;
  const int l15 = lane & 15, quad = lane >> 4;
  const int srow = tid >> 1, shalf = tid & 1;    // staging: row, 16-elem half of 32-chunk
  f32x4 acc[4][4];
  #pragma unroll
  for (int i = 0; i < 4; i++)
    #pragma unroll
    for (int j = 0; j < 4; j++) acc[i][j] = (f32x4){0.f, 0.f, 0.f, 0.f};
  const uint4* Bg = (const uint4*)(Bt + (size_t)(bn + srow) * KD);
  short* Asd = &As[srow * 40 + shalf * 16];
  short* Bsd = &Bs[srow * 40 + shalf * 16];
  #pragma unroll 2
  for (int kc = 0; kc < KD / 32; kc++) {
    if constexpr (sizeof(AT) == 4) {   // fp32 A: 16 floats -> 16 bf16
      const float4* Agf = (const float4*)(A + (size_t)(bm + srow) * KD) + kc * 8 + shalf * 4;
      const float4 f0 = Agf[0], f1 = Agf[1], f2 = Agf[2], f3 = Agf[3];
      unsigned short t16[16] = {
        f2b(f0.x), f2b(f0.y), f2b(f0.z), f2b(f0.w),
        f2b(f1.x), f2b(f1.y), f2b(f1.z), f2b(f1.w),
        f2b(f2.x), f2b(f2.y), f2b(f2.z), f2b(f2.w),
        f2b(f3.x), f2b(f3.y), f2b(f3.z), f2b(f3.w)};
      *(uint4*)&Asd[0] = *(uint4*)&t16[0];
      *(uint4*)&Asd[8] = *(uint4*)&t16[8];
    } else {                            // bf16 A
      const uint4* Ag = (const uint4*)(A + (size_t)(bm + srow) * KD);
      const uint4 a0 = Ag[kc * 4 + shalf * 2], a1 = Ag[kc * 4 + shalf * 2 + 1];
      *(uint4*)&Asd[0] = a0; *(uint4*)&Asd[8] = a1;
    }
    const uint4 b0 = Bg[kc * 4 + shalf * 2], b1 = Bg[kc * 4 + shalf * 2 + 1];
    *(uint4*)&Bsd[0] = b0; *(uint4*)&Bsd[8] = b1;
    __syncthreads();
    bf16x8 af[4], bf[4];
    #pragma unroll
    for (int tt = 0; tt < 4; tt++) {
      af[tt] = *(const bf16x8*)&As[(wm + tt * 16 + l15) * 40 + quad * 8];
      bf[tt] = *(const bf16x8*)&Bs[(wn + tt * 16 + l15) * 40 + quad * 8];
    }
    #pragma unroll
    for (int tm = 0; tm < 4; tm++)
      #pragma unroll
      for (int tn = 0; tn < 4; tn++)
        acc[tm][tn] = __builtin_amdgcn_mfma_f32_16x16x32_bf16(af[tm], bf[tn], acc[tm][tn], 0, 0, 0);
    __syncthreads();
  }
  #pragma unroll
  for (int tn = 0; tn < 4; tn++) {
    const int col = bn + wn + tn * 16 + l15;
    const float bv = bias[col];
    #pragma unroll
    for (int tm = 0; tm < 4; tm++) {
      const int row = bm + wm + tm * 16 + quad * 4;
      #pragma unroll
      for (int i = 0; i < 4; i++) {
        float v = acc[tm][tn][i] + bv;
        if constexpr (RELU) v = fmaxf(v, 0.f);
        stgi(C + (size_t)(row + i) * ldc + col, v);
      }
    }
  }
}

// ---------------- K2b: scores per row: e = exp(tanh(m@W1+b1)@W2+b2) ----------------
__global__ __launch_bounds__(256) void k_scores(const __hip_bfloat16* __restrict__ m,
    const float* __restrict__ W1, const float* __restrict__ b1,
    const float* __restrict__ W2, const float* __restrict__ b2,
    float* __restrict__ e) {
  const int row = blockIdx.x;        // b*512+s
  const int tid = threadIdx.x;       // 256
  __shared__ float ms[DD];
  __shared__ float as[DA];
  __shared__ float part[8][32];
  {
    const unsigned int mm = ((const unsigned int*)(m + (size_t)row * DD))[tid];
    ms[2 * tid] = bflo(mm); ms[2 * tid + 1] = bfhi(mm);
  }
  __syncthreads();
  const int a2 = tid & 31, seg = tid >> 5;
  float p = 0.f;
  if (a2 < DA) {
    const int kb = seg * 64;
    #pragma unroll 8
    for (int k = 0; k < 64; k++) p = fmaf(ms[kb + k], W1[(kb + k) * DA + a2], p);
  }
  part[seg][a2] = p;
  __syncthreads();
  if (tid < DA) {
    float a = b1[tid];
    #pragma unroll
    for (int s = 0; s < 8; s++) a += part[s][tid];
    as[tid] = tanhf(a);
  }
  __syncthreads();
  if (tid < RR) {
    float s = b2[tid];
    #pragma unroll
    for (int j = 0; j < DA; j++) s = fmaf(as[j], W2[j * RR + tid], s);
    e[row * RR + tid] = __expf(s);
  }
}

// ---------------- K3: per-(b,r) prefix scan -> inv[b,k,r] = 1/cumsum_k e ----------------
__global__ __launch_bounds__(64) void k_scan(const float* __restrict__ e, float* __restrict__ inv) {
  const int b = blockIdx.x / RR, r = blockIdx.x % RR;
  const int lane = threadIdx.x;  // 64
  float v[8];
  float sum = 0.f;
  #pragma unroll
  for (int i = 0; i < 8; i++) { v[i] = e[(b * SS + lane * 8 + i) * RR + r]; sum += v[i]; }
  float inc = sum;
  #pragma unroll
  for (int off = 1; off < 64; off <<= 1) {
    float n = __shfl_up(inc, off);
    if (lane >= off) inc += n;
  }
  float c = inc - sum;  // exclusive prefix
  #pragma unroll
  for (int i = 0; i < 8; i++) { c += v[i]; inv[(b * SS + lane * 8 + i) * RR + r] = 1.0f / c; }
}

// ---------------- K4: attention as streaming scan: M[t,d] = (1/R) sum_r cums(e*m)*inv ----
__global__ __launch_bounds__(128) void k_attn(const __hip_bfloat16* __restrict__ m,
    const float* __restrict__ e, const float* __restrict__ inv, __hip_bfloat16* __restrict__ M) {
  const int b = blockIdx.y;
  const int d = blockIdx.x * 128 + threadIdx.x;
  __shared__ float es[SS * RR];
  __shared__ float is[SS * RR];
  for (int i = threadIdx.x; i < SS * RR; i += 128) {
    es[i] = e[b * SS * RR + i];
    is[i] = inv[b * SS * RR + i];
  }
  __syncthreads();
  float num[RR];
  #pragma unroll
  for (int r = 0; r < RR; r++) num[r] = 0.f;
  const __hip_bfloat16* mb = m + (size_t)b * SS * DD + d;
  __hip_bfloat16* Mb = M + (size_t)b * SS * DD + d;
  #pragma unroll 4
  for (int k = 0; k < SS; k++) {
    const float mv = __bfloat162float(mb[(size_t)k * DD]);
    float acc = 0.f;
    #pragma unroll
    for (int r = 0; r < RR; r++) {
      num[r] = fmaf(es[k * RR + r], mv, num[r]);
      acc = fmaf(num[r], is[k * RR + r], acc);
    }
    Mb[(size_t)k * DD] = __float2bfloat16(acc * (1.0f / RR));
  }
}

// ---------------- K6 v8: v4 structure + exact-word pairs + XCD-verified fast path ------
// 256 blocks x 384 thr (v4 proven @1005us). Block = (batch b, j-slice g of 32 cols).
// Ring = PAIRS (h_bits fp32, word = salt + t), parity-2: NO ABA ever (word exact-unique
// within a dispatch; salt fresh per dispatch; 0xAA poison / bf16 data can never match).
// At kernel start each block publishes (salt, XCC_ID) to pub[] (dead W0T scratch) and
// polls its batch's 16 entries: if ALL 16 blocks share one XCD, the batch switches to the
// FAST protocol; else the exact v4 protocol (sc0 sc1 both sides).
// FAST protocol (liveness-hardened, cannot hang or accept stale data):
//   producer: sc0 store (updates the ONE shared XCD L2 -> quick visibility) immediately
//             followed by sc0 sc1 store of the same value (device scope -> guaranteed
//             global visibility for the fallback path).
//   consumer: spin on sc0 loads (shared-L2 RTT); every 4th failure also try the proven
//             sc0 sc1 load. Exact-match words: wrong data is never accepted; the sc1
//             store+load pair guarantees eventual progress regardless of sc0 semantics.
// Everything else identical to v4 (W rows in VGPRs, hs4/gis parity dbuf, 2 barriers/step,
// dedicated gate wave, gi prefetch wave).
template<typename GT>
__global__ __launch_bounds__(384) void k_gru(const __hip_bfloat16* __restrict__ WT,
    const GT* __restrict__ gi, const float* __restrict__ bh,
    unsigned int* __restrict__ ring, unsigned long long* __restrict__ pub,
    void* __restrict__ outv, const int* __restrict__ dflag) {
  const int lin = blockIdx.x, tid = threadIdx.x;
  const int xcd8 = lin & 7, within = lin >> 3;
  const int b = xcd8 + 8 * (within >> 4);
  const int g = within & 15;                     // j-slice: j in [g*32, g*32+32)
  const int f32o = dflag[0];
  const unsigned salt = ((const unsigned*)dflag)[1];
  const int c = tid >> 2, q = tid & 3;           // row c<96 (= gate*32+jj), k-quarter q<4
  const int col = ((c >> 5) << 9) + (g << 5) + (c & 31);
  __shared__ __align__(16) float hs4[2][4 * 132];   // parity x 4 padded quarters
  __shared__ float ghs[96];
  __shared__ float gis[2][96];
  __shared__ int sfast;
  // ---- one-time XCD co-residency verification (tid 0) ----
  if (tid == 0) {
    unsigned xcc;
    asm volatile("s_getreg_b32 %0, hwreg(HW_REG_XCC_ID)" : "=s"(xcc));
    unsigned long long* myp = pub + (b * 16 + g);
    const unsigned long long pv = ((unsigned long long)salt << 32) | (unsigned long long)xcc;
    asm volatile("global_store_dwordx2 %0, %1, off sc0 sc1" :: "v"(myp), "v"(pv) : "memory");
    int fast = 1;
    for (int i = 0; i < 16; i++) {
      const unsigned long long* p = pub + (b * 16 + i);
      unsigned long long v;
      do {
        asm volatile("global_load_dwordx2 %0, %1, off sc0 sc1\n\ts_waitcnt vmcnt(0)"
                     : "=v"(v) : "v"(p) : "memory");
      } while ((unsigned)(v >> 32) != salt);
      if ((unsigned)v != xcc) fast = 0;
    }
    sfast = fast;
  }
  // W quarter-row resident in registers: 128 bf16 = 16 uint4 (64 VGPRs)
  uint4 wr[16];
  {
    const uint4* wp = (const uint4*)(WT + (size_t)col * HH + q * 128);
    #pragma unroll
    for (int i = 0; i < 16; i++) wr[i] = wp[i];
  }
  const float bias_c = bh[col];
  // gi prefetch threads: tid in [256,352) <-> slot 0..95
  const int pslot = tid - 256;
  const bool pf = (pslot >= 0 && pslot < 96);
  const int gcol = pf ? (((pslot >> 5) << 9) + (g << 5) + (pslot & 31)) : 0;
  // gates threads: tid in [352,384) <-> jj 0..31
  const bool gt = (tid >= 352);
  const int jj = tid - 352;
  const int jg = (g << 5) + jj;
  const GT* gib = gi + (size_t)b * SS * G3;
  float gpre = pf ? ldgi(gib + gcol) : 0.f;
  __syncthreads();                               // sfast visible to all
  const int fastp = sfast;

  for (int t = 0; t < SS; t++) {
    const int par = t & 1;
    // ---- poll h_t pairs: tid<128 owns pair slots 4tid..4tid+3 (32B) ----
    if (tid < 128) {
      const unsigned want = salt + (unsigned)t;
      const uint4* src = (const uint4*)(ring + (size_t)(par * BB + b) * HH * 2) + tid * 2;
      uint4 va, vb;
      if (fastp) {
        int it = 0;
        for (;;) {
          asm volatile("global_load_dwordx4 %0, %2, off sc0\n\t"
                       "global_load_dwordx4 %1, %2, off offset:16 sc0\n\t"
                       "s_waitcnt vmcnt(0)"
                       : "=v"(va), "=v"(vb) : "v"(src) : "memory");
          if (((va.y ^ want) | (va.w ^ want) | (vb.y ^ want) | (vb.w ^ want)) == 0u) break;
          if ((++it & 3) == 0) {
            asm volatile("global_load_dwordx4 %0, %2, off sc0 sc1\n\t"
                         "global_load_dwordx4 %1, %2, off offset:16 sc0 sc1\n\t"
                         "s_waitcnt vmcnt(0)"
                         : "=v"(va), "=v"(vb) : "v"(src) : "memory");
            if (((va.y ^ want) | (va.w ^ want) | (vb.y ^ want) | (vb.w ^ want)) == 0u) break;
          }
        }
      } else {
        for (;;) {
          asm volatile("global_load_dwordx4 %0, %2, off sc0 sc1\n\t"
                       "global_load_dwordx4 %1, %2, off offset:16 sc0 sc1\n\t"
                       "s_waitcnt vmcnt(0)"
                       : "=v"(va), "=v"(vb) : "v"(src) : "memory");
          if (((va.y ^ want) | (va.w ^ want) | (vb.y ^ want) | (vb.w ^ want)) == 0u) break;
        }
      }
      float* dq = &hs4[par][(tid >> 5) * 132 + ((tid * 4) & 127)];
      dq[0] = __uint_as_float(va.x); dq[1] = __uint_as_float(va.z);
      dq[2] = __uint_as_float(vb.x); dq[3] = __uint_as_float(vb.z);
    }
    if (pf) gis[par][pslot] = gpre;
    __syncthreads();                                    // #1 (stage -> dot)
    if (pf && t + 1 < SS) gpre = ldgi(gib + (size_t)(t + 1) * G3 + gcol);  // overlap dot
    // dot: row col, k in [q*128, q*128+128)
    float a0 = 0.f, a1 = 0.f, a2 = 0.f, a3 = 0.f;
    const float4* hp = (const float4*)&hs4[par][q * 132];
    #pragma unroll
    for (int i = 0; i < 16; i++) {
      const uint4 w = wr[i];
      const float4 ha = hp[2 * i];
      const float4 hb = hp[2 * i + 1];
      a0 = fmaf(ha.x, bflo(w.x), a0); a1 = fmaf(ha.y, bfhi(w.x), a1);
      a2 = fmaf(ha.z, bflo(w.y), a2); a3 = fmaf(ha.w, bfhi(w.y), a3);
      a0 = fmaf(hb.x, bflo(w.z), a0); a1 = fmaf(hb.y, bfhi(w.z), a1);
      a2 = fmaf(hb.z, bflo(w.w), a2); a3 = fmaf(hb.w, bfhi(w.w), a3);
    }
    float acc = (a0 + a1) + (a2 + a3);
    acc += __shfl_xor(acc, 1);   // reduce across q (lane bits 0..1)
    acc += __shfl_xor(acc, 2);
    if (q == 0) ghs[c] = acc + bias_c;
    __syncthreads();                                    // #2 (ghs/gis -> gates; hs4 WAR)
    if (gt) {
      const float ghr = ghs[jj], ghz = ghs[32 + jj], ghn = ghs[64 + jj];
      const float gir = gis[par][jj], giz = gis[par][32 + jj], gin = gis[par][64 + jj];
      const float r = 1.f / (1.f + __expf(-(gir + ghr)));
      const float z = 1.f / (1.f + __expf(-(giz + ghz)));
      const float nx = gin + r * ghn;
      const float n = 1.f - 2.f / (__expf(2.f * nx) + 1.f);   // tanh
      const float hprev = hs4[par][(jg >> 7) * 132 + (jg & 127)];
      const float hnew = n + z * (hprev - n);
      // pair store: (h_bits, salt + t + 1) as one aligned 8B dwordx2
      unsigned int* pP = ring + ((size_t)(((t + 1) & 1) * BB + b) * HH + jg) * 2;
      const unsigned long long pk =
          (unsigned long long)__float_as_uint(hnew) |
          ((unsigned long long)(salt + (unsigned)(t + 1)) << 32);
      if (fastp) {
        asm volatile("global_store_dwordx2 %0, %1, off sc0" :: "v"(pP), "v"(pk) : "memory");
        asm volatile("global_store_dwordx2 %0, %1, off sc0 sc1" :: "v"(pP), "v"(pk) : "memory");
      } else {
        asm volatile("global_store_dwordx2 %0, %1, off sc0 sc1" :: "v"(pP), "v"(pk) : "memory");
      }
      const size_t oi = ((size_t)b * SS + t) * HH + jg;
      if (f32o) ((float*)outv)[oi] = hnew;
      else ((__hip_bfloat16*)outv)[oi] = __float2bfloat16(hnew);
    }
    // no barrier #3: hs4/gis parity double-buffered; ghs WAR fenced by barrier #1
  }
}

extern "C" void kernel_launch(void* const* d_in, const int* in_sizes, int n_in,
                              void* d_out, int out_size, void* d_ws, size_t ws_size,
                              hipStream_t stream) {
  char* wsb = (char*)d_ws;
  unsigned int* ring = (unsigned int*)(wsb + OFF_H);
  int* dflag  = (int*)(wsb + OFF_DF);
  float* cx   = (float*)(wsb + OFF_CX);
  float* cW0  = (float*)(wsb + OFF_CW0);
  float* cb0  = (float*)(wsb + OFF_CB0);
  float* cW1  = (float*)(wsb + OFF_CW1);
  float* cb1  = (float*)(wsb + OFF_CB1);
  float* cW2  = (float*)(wsb + OFF_CW2);
  float* cb2  = (float*)(wsb + OFF_CB2);
  float* cWih = (float*)(wsb + OFF_CWIH);
  float* cWhh = (float*)(wsb + OFF_CWHH);
  float* cbi  = (float*)(wsb + OFF_CBI);
  float* cbh  = (float*)(wsb + OFF_CBH);
  __hip_bfloat16* WT   = (__hip_bfloat16*)(wsb + OFF_WT);
  __hip_bfloat16* WihT = (__hip_bfloat16*)(wsb + OFF_WIHT);
  __hip_bfloat16* W0T  = (__hip_bfloat16*)(wsb + OFF_W0T);
  unsigned long long* pub = (unsigned long long*)(wsb + OFF_W0T);  // reuse after GEMM#1
  __hip_bfloat16* Mm   = (__hip_bfloat16*)(wsb + OFF_MM);
  __hip_bfloat16* m    = (__hip_bfloat16*)(wsb + OFF_M);
  float* e   = (float*)(wsb + OFF_E);
  float* inv = (float*)(wsb + OFF_INV);
  void* gip  = (void*)(wsb + OFF_GI);
  const bool gi32 = (ws_size >= NEED_GI32);   // constant across calls -> same work every call

  // k_detect seeds the pair ring (ws is poisoned 0xAA before every call) and sets dflag/salt
  k_detect<<<1, 256, 0, stream>>>((const unsigned short*)d_in[0], dflag, (uint4*)ring);

  CvtArgs ca;
  float* dsts[11] = {cx, cW0, cb0, cW1, cb1, cW2, cb2, cWih, cWhh, cbi, cbh};
  const int ns[11] = {BB * SS * IN_, IN_ * DD, DD, DD * DA, DA, DA * RR, RR,
                      DD * G3, HH * G3, G3, G3};
  for (int i = 0; i < 11; i++) { ca.src[i] = d_in[i]; ca.dst[i] = dsts[i]; ca.n[i] = ns[i]; }
  k_cvt<<<dim3(128, 11), 256, 0, stream>>>(ca, dflag);

  k_transpose3<<<1600, dim3(32, 32), 0, stream>>>(cWhh, cWih, cW0, WT, WihT, W0T);
  // m = relu(x @ W0 + b0) via MFMA (fp32 A staged to bf16)
  k_gemm<float, __hip_bfloat16, IN_, true>
      <<<dim3(DD / 128, (BB * SS) / 128), 256, 0, stream>>>(cx, W0T, cb0, m, DD);
  k_scores<<<BB * SS, 256, 0, stream>>>(m, cW1, cb1, cW2, cb2, e);
  k_scan<<<BB * RR, 64, 0, stream>>>(e, inv);
  k_attn<<<dim3(4, BB), 128, 0, stream>>>(m, e, inv, Mm);
  if (gi32) {
    k_gemm<__hip_bfloat16, float, DD, false>
        <<<dim3(G3 / 128, (BB * SS) / 128), 256, 0, stream>>>(Mm, WihT, cbi, (float*)gip, G3);
    k_gru<float><<<256, 384, 0, stream>>>(WT, (const float*)gip, cbh, ring, pub, d_out, dflag);
  } else {
    k_gemm<__hip_bfloat16, __hip_bfloat16, DD, false>
        <<<dim3(G3 / 128, (BB * SS) / 128), 256, 0, stream>>>(Mm, WihT, cbi,
                                                              (__hip_bfloat16*)gip, G3);
    k_gru<__hip_bfloat16><<<256, 384, 0, stream>>>(WT, (const __hip_bfloat16*)gip, cbh,
                                                   ring, pub, d_out, dflag);
  }
}

// Round 7
// 1245.686 us; speedup vs baseline: 1.1474x; 1.0602x over previous
//
#include <hip/hip_runtime.h>
#include <hip/hip_bf16.h>

// Problem dims
#define BB 16
#define SS 512
#define IN_ 128
#define DD 512
#define HH 512
#define DA 30
#define RR 10
#define G3 1536   // 3*H

// ---- ws layout (bytes) ----
constexpr size_t OFF_H    = 0;                        // tagged h ring u32[2][16][512]: 65,536
constexpr size_t OFF_DF   = 131072;                   // dtype flag: 256
constexpr size_t OFF_CX   = OFF_DF   + 256;           // canonical fp32 inputs
constexpr size_t OFF_CW0  = OFF_CX   + 4194304;
constexpr size_t OFF_CB0  = OFF_CW0  + 262144;
constexpr size_t OFF_CW1  = OFF_CB0  + 2048;
constexpr size_t OFF_CB1  = OFF_CW1  + 61440;
constexpr size_t OFF_CW2  = OFF_CB1  + 256;
constexpr size_t OFF_CB2  = OFF_CW2  + 2048;
constexpr size_t OFF_CWIH = OFF_CB2  + 256;
constexpr size_t OFF_CWHH = OFF_CWIH + 3145728;
constexpr size_t OFF_CBI  = OFF_CWHH + 3145728;
constexpr size_t OFF_CBH  = OFF_CBI  + 6144;
constexpr size_t OFF_WT   = OFF_CBH  + 6144;          // W_hh^T bf16 [1536][512]
constexpr size_t OFF_WIHT = OFF_WT   + 1572864;       // W_ih^T bf16 [1536][512]
constexpr size_t OFF_W0T  = OFF_WIHT + 1572864;       // W0^T bf16 [512][128]
constexpr size_t OFF_MM   = OFF_W0T  + 131072;        // M bf16 [8192][512]
constexpr size_t OFF_BIG  = OFF_MM   + 8388608;
constexpr size_t OFF_M    = OFF_BIG;                  // m bf16 [8192][512]
constexpr size_t OFF_E    = OFF_BIG  + 8388608;       // e f32 [8192][10]
constexpr size_t OFF_INV  = OFF_E    + 327680;        // inv f32
constexpr size_t OFF_GI   = OFF_BIG;                  // gi aliases m/e/inv (dead after k_attn)
constexpr size_t NEED_GI32 = OFF_BIG + 50331648;      // gi fp32 path total

typedef __attribute__((ext_vector_type(8))) short bf16x8;
typedef __attribute__((ext_vector_type(4))) float f32x4;

__device__ __forceinline__ float bflo(unsigned int u) { return __uint_as_float(u << 16); }
__device__ __forceinline__ float bfhi(unsigned int u) { return __uint_as_float(u & 0xffff0000u); }
__device__ __forceinline__ float bf1(unsigned short u) { return __uint_as_float(((unsigned int)u) << 16); }
__device__ __forceinline__ unsigned short f2b(float f) {
  __hip_bfloat16 h = __float2bfloat16(f);
  return *(unsigned short*)&h;
}

__device__ __forceinline__ float ldgi(const float* p) { return *p; }
__device__ __forceinline__ float ldgi(const __hip_bfloat16* p) { return __bfloat162float(*p); }
__device__ __forceinline__ void stgi(float* p, float v) { *p = v; }
__device__ __forceinline__ void stgi(__hip_bfloat16* p, float v) { *p = __float2bfloat16(v); }

// ---------------- K0a: detect input dtype + zero the h ring ----------------
__global__ __launch_bounds__(256) void k_detect(const unsigned short* __restrict__ xs,
                                                int* __restrict__ dflag,
                                                uint4* __restrict__ hz) {
  const int tid = threadIdx.x;
  // zero tagged h ring: 65,536 B = 4096 uint4 (bits 0 == h=0.0 with tag 0)
  const uint4 z = {0u, 0u, 0u, 0u};
  #pragma unroll
  for (int i = 0; i < 16; i++) hz[tid + i * 256] = z;
  int bad = 0;
  for (int i = tid; i < 8192; i += 256) {
    const float v = bf1(xs[i]);
    if (!(fabsf(v) < 1.0e3f)) bad++;   // NaN also counts
  }
  __shared__ int s;
  if (tid == 0) s = 0;
  __syncthreads();
  atomicAdd(&s, bad);
  __syncthreads();
  if (tid == 0) dflag[0] = (s > 16) ? 1 : 0;   // 1 = fp32 buffers, 0 = bf16 buffers
}

// ---------------- K0b: canonicalize all inputs to fp32 ----------------
struct CvtArgs { const void* src[11]; float* dst[11]; int n[11]; };
__global__ __launch_bounds__(256) void k_cvt(CvtArgs a, const int* __restrict__ dflag) {
  const int ai = blockIdx.y;
  const int n = a.n[ai];
  const int stride = gridDim.x * blockDim.x;
  const int f32 = dflag[0];
  float* dst = a.dst[ai];
  if (f32) {
    const float* src = (const float*)a.src[ai];
    for (int i = blockIdx.x * blockDim.x + threadIdx.x; i < n; i += stride) dst[i] = src[i];
  } else {
    const unsigned short* src = (const unsigned short*)a.src[ai];
    for (int i = blockIdx.x * blockDim.x + threadIdx.x; i < n; i += stride) dst[i] = bf1(src[i]);
  }
}

// ---------------- K1: fused transpose of W_hh, W_ih (512x1536) and W0 (128x512) ------
__global__ __launch_bounds__(1024) void k_transpose3(const float* __restrict__ Whh,
    const float* __restrict__ Wih, const float* __restrict__ W0,
    __hip_bfloat16* __restrict__ WhhT, __hip_bfloat16* __restrict__ WihT,
    __hip_bfloat16* __restrict__ W0T) {
  __shared__ float tile[32][33];
  int id = blockIdx.x;
  const float* W; __hip_bfloat16* WT; int R, C, tx, ty;
  if (id < 768)       { W = Whh; WT = WhhT; R = DD;  C = G3; tx = id % 48; ty = id / 48; }
  else if (id < 1536) { id -= 768;  W = Wih; WT = WihT; R = DD;  C = G3; tx = id % 48; ty = id / 48; }
  else                { id -= 1536; W = W0;  WT = W0T;  R = IN_; C = DD; tx = id % 16; ty = id / 16; }
  const int c0 = tx * 32, k0 = ty * 32;
  tile[threadIdx.y][threadIdx.x] = W[(k0 + threadIdx.y) * C + c0 + threadIdx.x];
  __syncthreads();
  WT[(c0 + threadIdx.y) * R + k0 + threadIdx.x] = __float2bfloat16(tile[threadIdx.x][threadIdx.y]);
}

// ---------------- K5: unified MFMA GEMM: C[M][N] = A[M][KD] @ Bt[N][KD]^T + bias ------
// Tile 128x128, 4 waves (2x2 of 64x64), BK=32. A staged fp32->bf16 or bf16 direct.
// C/D frag: col=lane&15, row=quad*4+reg (m89-verified).
template<typename AT, typename GT, int KD, bool RELU>
__global__ __launch_bounds__(256) void k_gemm(const AT* __restrict__ A,
    const __hip_bfloat16* __restrict__ Bt, const float* __restrict__ bias,
    GT* __restrict__ C, int ldc) {
  __shared__ short As[128 * 40];   // 128 rows x 32 k, stride 40 (bank de-phase)
  __shared__ short Bs[128 * 40];
  const int tid = threadIdx.x;
  const int bn = blockIdx.x * 128, bm = blockIdx.y * 128;
  const int lane = tid & 63, w = tid >> 6;
  const int wm = (w >> 1) * 64, wn = (w & 1) * 64;
  const int l15 = lane & 15, quad = lane >> 4;
  const int srow = tid >> 1, shalf = tid & 1;    // staging: row, 16-elem half of 32-chunk
  f32x4 acc[4][4];
  #pragma unroll
  for (int i = 0; i < 4; i++)
    #pragma unroll
    for (int j = 0; j < 4; j++) acc[i][j] = (f32x4){0.f, 0.f, 0.f, 0.f};
  const uint4* Bg = (const uint4*)(Bt + (size_t)(bn + srow) * KD);
  short* Asd = &As[srow * 40 + shalf * 16];
  short* Bsd = &Bs[srow * 40 + shalf * 16];
  #pragma unroll 2
  for (int kc = 0; kc < KD / 32; kc++) {
    if constexpr (sizeof(AT) == 4) {   // fp32 A: 16 floats -> 16 bf16
      const float4* Agf = (const float4*)(A + (size_t)(bm + srow) * KD) + kc * 8 + shalf * 4;
      const float4 f0 = Agf[0], f1 = Agf[1], f2 = Agf[2], f3 = Agf[3];
      unsigned short t16[16] = {
        f2b(f0.x), f2b(f0.y), f2b(f0.z), f2b(f0.w),
        f2b(f1.x), f2b(f1.y), f2b(f1.z), f2b(f1.w),
        f2b(f2.x), f2b(f2.y), f2b(f2.z), f2b(f2.w),
        f2b(f3.x), f2b(f3.y), f2b(f3.z), f2b(f3.w)};
      *(uint4*)&Asd[0] = *(uint4*)&t16[0];
      *(uint4*)&Asd[8] = *(uint4*)&t16[8];
    } else {                            // bf16 A
      const uint4* Ag = (const uint4*)(A + (size_t)(bm + srow) * KD);
      const uint4 a0 = Ag[kc * 4 + shalf * 2], a1 = Ag[kc * 4 + shalf * 2 + 1];
      *(uint4*)&Asd[0] = a0; *(uint4*)&Asd[8] = a1;
    }
    const uint4 b0 = Bg[kc * 4 + shalf * 2], b1 = Bg[kc * 4 + shalf * 2 + 1];
    *(uint4*)&Bsd[0] = b0; *(uint4*)&Bsd[8] = b1;
    __syncthreads();
    bf16x8 af[4], bf[4];
    #pragma unroll
    for (int tt = 0; tt < 4; tt++) {
      af[tt] = *(const bf16x8*)&As[(wm + tt * 16 + l15) * 40 + quad * 8];
      bf[tt] = *(const bf16x8*)&Bs[(wn + tt * 16 + l15) * 40 + quad * 8];
    }
    #pragma unroll
    for (int tm = 0; tm < 4; tm++)
      #pragma unroll
      for (int tn = 0; tn < 4; tn++)
        acc[tm][tn] = __builtin_amdgcn_mfma_f32_16x16x32_bf16(af[tm], bf[tn], acc[tm][tn], 0, 0, 0);
    __syncthreads();
  }
  #pragma unroll
  for (int tn = 0; tn < 4; tn++) {
    const int col = bn + wn + tn * 16 + l15;
    const float bv = bias[col];
    #pragma unroll
    for (int tm = 0; tm < 4; tm++) {
      const int row = bm + wm + tm * 16 + quad * 4;
      #pragma unroll
      for (int i = 0; i < 4; i++) {
        float v = acc[tm][tn][i] + bv;
        if constexpr (RELU) v = fmaxf(v, 0.f);
        stgi(C + (size_t)(row + i) * ldc + col, v);
      }
    }
  }
}

// ---------------- K2b: scores per row: e = exp(tanh(m@W1+b1)@W2+b2) ----------------
__global__ __launch_bounds__(256) void k_scores(const __hip_bfloat16* __restrict__ m,
    const float* __restrict__ W1, const float* __restrict__ b1,
    const float* __restrict__ W2, const float* __restrict__ b2,
    float* __restrict__ e) {
  const int row = blockIdx.x;        // b*512+s
  const int tid = threadIdx.x;       // 256
  __shared__ float ms[DD];
  __shared__ float as[DA];
  __shared__ float part[8][32];
  {
    const unsigned int mm = ((const unsigned int*)(m + (size_t)row * DD))[tid];
    ms[2 * tid] = bflo(mm); ms[2 * tid + 1] = bfhi(mm);
  }
  __syncthreads();
  const int a2 = tid & 31, seg = tid >> 5;
  float p = 0.f;
  if (a2 < DA) {
    const int kb = seg * 64;
    #pragma unroll 8
    for (int k = 0; k < 64; k++) p = fmaf(ms[kb + k], W1[(kb + k) * DA + a2], p);
  }
  part[seg][a2] = p;
  __syncthreads();
  if (tid < DA) {
    float a = b1[tid];
    #pragma unroll
    for (int s = 0; s < 8; s++) a += part[s][tid];
    as[tid] = tanhf(a);
  }
  __syncthreads();
  if (tid < RR) {
    float s = b2[tid];
    #pragma unroll
    for (int j = 0; j < DA; j++) s = fmaf(as[j], W2[j * RR + tid], s);
    e[row * RR + tid] = __expf(s);
  }
}

// ---------------- K3: per-(b,r) prefix scan -> inv[b,k,r] = 1/cumsum_k e ----------------
__global__ __launch_bounds__(64) void k_scan(const float* __restrict__ e, float* __restrict__ inv) {
  const int b = blockIdx.x / RR, r = blockIdx.x % RR;
  const int lane = threadIdx.x;  // 64
  float v[8];
  float sum = 0.f;
  #pragma unroll
  for (int i = 0; i < 8; i++) { v[i] = e[(b * SS + lane * 8 + i) * RR + r]; sum += v[i]; }
  float inc = sum;
  #pragma unroll
  for (int off = 1; off < 64; off <<= 1) {
    float n = __shfl_up(inc, off);
    if (lane >= off) inc += n;
  }
  float c = inc - sum;  // exclusive prefix
  #pragma unroll
  for (int i = 0; i < 8; i++) { c += v[i]; inv[(b * SS + lane * 8 + i) * RR + r] = 1.0f / c; }
}

// ---------------- K4: attention as streaming scan: M[t,d] = (1/R) sum_r cums(e*m)*inv ----
__global__ __launch_bounds__(128) void k_attn(const __hip_bfloat16* __restrict__ m,
    const float* __restrict__ e, const float* __restrict__ inv, __hip_bfloat16* __restrict__ M) {
  const int b = blockIdx.y;
  const int d = blockIdx.x * 128 + threadIdx.x;
  __shared__ float es[SS * RR];
  __shared__ float is[SS * RR];
  for (int i = threadIdx.x; i < SS * RR; i += 128) {
    es[i] = e[b * SS * RR + i];
    is[i] = inv[b * SS * RR + i];
  }
  __syncthreads();
  float num[RR];
  #pragma unroll
  for (int r = 0; r < RR; r++) num[r] = 0.f;
  const __hip_bfloat16* mb = m + (size_t)b * SS * DD + d;
  __hip_bfloat16* Mb = M + (size_t)b * SS * DD + d;
  #pragma unroll 4
  for (int k = 0; k < SS; k++) {
    const float mv = __bfloat162float(mb[(size_t)k * DD]);
    float acc = 0.f;
    #pragma unroll
    for (int r = 0; r < RR; r++) {
      num[r] = fmaf(es[k * RR + r], mv, num[r]);
      acc = fmaf(num[r], is[k * RR + r], acc);
    }
    Mb[(size_t)k * DD] = __float2bfloat16(acc * (1.0f / RR));
  }
}

// ---------------- K6 v11: EXACT v4 protocol + 2-deep poll in ONE asm block -------------
// 256 blocks x 384 thr (v4 proven @1005us). Block = (batch b, j-slice g of 32 cols).
// v4's u32 tagged ring (2-bit step tag in fp32 LSBs, parity-2), agent-scope stores,
// sc0 sc1 polls (v7/v9 hang lesson: sc0-only loads can serve a stale line forever).
// ONE change vs v4: the poll keeps TWO 4-dword load groups in flight, halving the
// arrival-detection quantum from ~RTT to ~RTT/2. Implemented as a single self-contained
// asm block (r6 lesson: tied 128-bit asm operands unsupported; cross-block in-flight
// regs are compiler-unsafe): scalar dword loads, VALU tag-check, wave-uniform
// s_cbranch_vccz exit, positional vmcnt(4) ping-pong, vmcnt(0) drain on exit.
// Wave-uniform exit is safe: a passed lane's re-load stays valid because the parity-2
// slot cannot be overwritten until every block's step-t gates ran (v4 dependency chain).
template<typename GT>
__global__ __launch_bounds__(384) void k_gru(const __hip_bfloat16* __restrict__ WT,
    const GT* __restrict__ gi, const float* __restrict__ bh,
    unsigned int* __restrict__ hslots, void* __restrict__ outv,
    const int* __restrict__ dflag) {
  const int lin = blockIdx.x, tid = threadIdx.x;
  const int xcd = lin & 7, within = lin >> 3;
  const int b = xcd + 8 * (within >> 4);
  const int g = within & 15;                     // j-slice: j in [g*32, g*32+32)
  const int f32o = dflag[0];
  const int c = tid >> 2, q = tid & 3;           // row c<96 (= gate*32+jj), k-quarter q<4
  const int col = ((c >> 5) << 9) + (g << 5) + (c & 31);
  __shared__ __align__(16) float hs4[2][4 * 132];   // parity x 4 padded quarters
  __shared__ float ghs[96];
  __shared__ float gis[2][96];
  // W quarter-row resident in registers: 128 bf16 = 16 uint4 (64 VGPRs)
  uint4 wr[16];
  {
    const uint4* wp = (const uint4*)(WT + (size_t)col * HH + q * 128);
    #pragma unroll
    for (int i = 0; i < 16; i++) wr[i] = wp[i];
  }
  const float bias_c = bh[col];
  // gi prefetch threads: tid in [256,352) <-> slot 0..95
  const int pslot = tid - 256;
  const bool pf = (pslot >= 0 && pslot < 96);
  const int gcol = pf ? (((pslot >> 5) << 9) + (g << 5) + (pslot & 31)) : 0;
  // gates threads: tid in [352,384) <-> jj 0..31
  const bool gt = (tid >= 352);
  const int jj = tid - 352;
  const int jg = (g << 5) + jj;
  unsigned int* s0 = hslots + b * HH;
  unsigned int* s1 = hslots + BB * HH + b * HH;
  const GT* gib = gi + (size_t)b * SS * G3;
  float gpre = pf ? ldgi(gib + gcol) : 0.f;

  for (int t = 0; t < SS; t++) {
    const int par = t & 1;
    unsigned int* cur = par ? s1 : s0;
    unsigned int* nxt = par ? s0 : s1;
    // poll+stage h_t: tid<128 polls 4 dwords (slots 4tid..4tid+3, same quarter).
    // 2-deep pipelined: two 4-dword groups in flight; detection quantum ~RTT/2.
    if (tid < 128) {
      const unsigned want = ((unsigned)t) & 3u;
      const unsigned int* src = cur + tid * 4;
      unsigned r0, r1, r2, r3, pa0, pa1, pa2, pa3, pb0, pb1, pb2, pb3, t0, t1;
      asm volatile(
        "global_load_dword %[a0], %[sp], off sc0 sc1\n\t"
        "global_load_dword %[a1], %[sp], off offset:4 sc0 sc1\n\t"
        "global_load_dword %[a2], %[sp], off offset:8 sc0 sc1\n\t"
        "global_load_dword %[a3], %[sp], off offset:12 sc0 sc1\n\t"
        "global_load_dword %[b0], %[sp], off sc0 sc1\n\t"
        "global_load_dword %[b1], %[sp], off offset:4 sc0 sc1\n\t"
        "global_load_dword %[b2], %[sp], off offset:8 sc0 sc1\n\t"
        "global_load_dword %[b3], %[sp], off offset:12 sc0 sc1\n\t"
        "Lhead%=:\n\t"
        "s_waitcnt vmcnt(4)\n\t"                    // group A complete (B in flight)
        "v_xor_b32 %[t0], %[a0], %[wv]\n\t"
        "v_xor_b32 %[t1], %[a1], %[wv]\n\t"
        "v_or_b32  %[t0], %[t0], %[t1]\n\t"
        "v_xor_b32 %[t1], %[a2], %[wv]\n\t"
        "v_or_b32  %[t0], %[t0], %[t1]\n\t"
        "v_xor_b32 %[t1], %[a3], %[wv]\n\t"
        "v_or_b32  %[t0], %[t0], %[t1]\n\t"
        "v_and_b32 %[t0], 3, %[t0]\n\t"
        "v_cmp_ne_u32 vcc, 0, %[t0]\n\t"
        "s_cbranch_vccz LgotA%=\n\t"                // all 64 lanes tag-match on A
        "global_load_dword %[a0], %[sp], off sc0 sc1\n\t"
        "global_load_dword %[a1], %[sp], off offset:4 sc0 sc1\n\t"
        "global_load_dword %[a2], %[sp], off offset:8 sc0 sc1\n\t"
        "global_load_dword %[a3], %[sp], off offset:12 sc0 sc1\n\t"
        "s_waitcnt vmcnt(4)\n\t"                    // group B complete (A in flight)
        "v_xor_b32 %[t0], %[b0], %[wv]\n\t"
        "v_xor_b32 %[t1], %[b1], %[wv]\n\t"
        "v_or_b32  %[t0], %[t0], %[t1]\n\t"
        "v_xor_b32 %[t1], %[b2], %[wv]\n\t"
        "v_or_b32  %[t0], %[t0], %[t1]\n\t"
        "v_xor_b32 %[t1], %[b3], %[wv]\n\t"
        "v_or_b32  %[t0], %[t0], %[t1]\n\t"
        "v_and_b32 %[t0], 3, %[t0]\n\t"
        "v_cmp_ne_u32 vcc, 0, %[t0]\n\t"
        "s_cbranch_vccz LgotB%=\n\t"
        "global_load_dword %[b0], %[sp], off sc0 sc1\n\t"
        "global_load_dword %[b1], %[sp], off offset:4 sc0 sc1\n\t"
        "global_load_dword %[b2], %[sp], off offset:8 sc0 sc1\n\t"
        "global_load_dword %[b3], %[sp], off offset:12 sc0 sc1\n\t"
        "s_branch Lhead%=\n\t"
        "LgotA%=:\n\t"
        "s_waitcnt vmcnt(0)\n\t"                    // drain B's pending reg writes
        "v_mov_b32 %[r0], %[a0]\n\t"
        "v_mov_b32 %[r1], %[a1]\n\t"
        "v_mov_b32 %[r2], %[a2]\n\t"
        "v_mov_b32 %[r3], %[a3]\n\t"
        "s_branch Ldone%=\n\t"
        "LgotB%=:\n\t"
        "s_waitcnt vmcnt(0)\n\t"                    // drain A's pending reg writes
        "v_mov_b32 %[r0], %[b0]\n\t"
        "v_mov_b32 %[r1], %[b1]\n\t"
        "v_mov_b32 %[r2], %[b2]\n\t"
        "v_mov_b32 %[r3], %[b3]\n\t"
        "Ldone%=:"
        : [r0]"=&v"(r0), [r1]"=&v"(r1), [r2]"=&v"(r2), [r3]"=&v"(r3),
          [a0]"=&v"(pa0), [a1]"=&v"(pa1), [a2]"=&v"(pa2), [a3]"=&v"(pa3),
          [b0]"=&v"(pb0), [b1]"=&v"(pb1), [b2]"=&v"(pb2), [b3]"=&v"(pb3),
          [t0]"=&v"(t0), [t1]"=&v"(t1)
        : [sp]"v"(src), [wv]"v"(want)
        : "memory", "vcc");
      float* dq = &hs4[par][(tid >> 5) * 132 + ((tid * 4) & 127)];
      dq[0] = __uint_as_float(r0); dq[1] = __uint_as_float(r1);
      dq[2] = __uint_as_float(r2); dq[3] = __uint_as_float(r3);
    }
    if (pf) gis[par][pslot] = gpre;
    __syncthreads();                                    // #1 (stage -> dot)
    if (pf && t + 1 < SS) gpre = ldgi(gib + (size_t)(t + 1) * G3 + gcol);  // overlap dot
    // dot: row col, k in [q*128, q*128+128)
    float a0 = 0.f, a1 = 0.f, a2 = 0.f, a3 = 0.f;
    const float4* hp = (const float4*)&hs4[par][q * 132];
    #pragma unroll
    for (int i = 0; i < 16; i++) {
      const uint4 w = wr[i];
      const float4 ha = hp[2 * i];
      const float4 hb = hp[2 * i + 1];
      a0 = fmaf(ha.x, bflo(w.x), a0); a1 = fmaf(ha.y, bfhi(w.x), a1);
      a2 = fmaf(ha.z, bflo(w.y), a2); a3 = fmaf(ha.w, bfhi(w.y), a3);
      a0 = fmaf(hb.x, bflo(w.z), a0); a1 = fmaf(hb.y, bfhi(w.z), a1);
      a2 = fmaf(hb.z, bflo(w.w), a2); a3 = fmaf(hb.w, bfhi(w.w), a3);
    }
    float acc = (a0 + a1) + (a2 + a3);
    acc += __shfl_xor(acc, 1);   // reduce across q (lane bits 0..1)
    acc += __shfl_xor(acc, 2);
    if (q == 0) ghs[c] = acc + bias_c;
    __syncthreads();                                    // #2 (ghs/gis -> gates; hs4 WAR)
    if (gt) {
      const float ghr = ghs[jj], ghz = ghs[32 + jj], ghn = ghs[64 + jj];
      const float gir = gis[par][jj], giz = gis[par][32 + jj], gin = gis[par][64 + jj];
      const float r = 1.f / (1.f + __expf(-(gir + ghr)));
      const float z = 1.f / (1.f + __expf(-(giz + ghz)));
      const float nx = gin + r * ghn;
      const float n = 1.f - 2.f / (__expf(2.f * nx) + 1.f);   // tanh
      const float hprev = hs4[par][(jg >> 7) * 132 + (jg & 127)];
      const float hnew = n + z * (hprev - n);
      const unsigned pk = (__float_as_uint(hnew) & ~3u) | (((unsigned)(t + 1)) & 3u);
      __hip_atomic_store(nxt + jg, pk, __ATOMIC_RELAXED, __HIP_MEMORY_SCOPE_AGENT);
      const size_t oi = ((size_t)b * SS + t) * HH + jg;
      if (f32o) ((float*)outv)[oi] = hnew;
      else ((__hip_bfloat16*)outv)[oi] = __float2bfloat16(hnew);
    }
    // no barrier #3: hs4/gis parity double-buffered; ghs WAR fenced by barrier #1
  }
}

extern "C" void kernel_launch(void* const* d_in, const int* in_sizes, int n_in,
                              void* d_out, int out_size, void* d_ws, size_t ws_size,
                              hipStream_t stream) {
  char* wsb = (char*)d_ws;
  unsigned int* hslots = (unsigned int*)(wsb + OFF_H);
  int* dflag  = (int*)(wsb + OFF_DF);
  float* cx   = (float*)(wsb + OFF_CX);
  float* cW0  = (float*)(wsb + OFF_CW0);
  float* cb0  = (float*)(wsb + OFF_CB0);
  float* cW1  = (float*)(wsb + OFF_CW1);
  float* cb1  = (float*)(wsb + OFF_CB1);
  float* cW2  = (float*)(wsb + OFF_CW2);
  float* cb2  = (float*)(wsb + OFF_CB2);
  float* cWih = (float*)(wsb + OFF_CWIH);
  float* cWhh = (float*)(wsb + OFF_CWHH);
  float* cbi  = (float*)(wsb + OFF_CBI);
  float* cbh  = (float*)(wsb + OFF_CBH);
  __hip_bfloat16* WT   = (__hip_bfloat16*)(wsb + OFF_WT);
  __hip_bfloat16* WihT = (__hip_bfloat16*)(wsb + OFF_WIHT);
  __hip_bfloat16* W0T  = (__hip_bfloat16*)(wsb + OFF_W0T);
  __hip_bfloat16* Mm   = (__hip_bfloat16*)(wsb + OFF_MM);
  __hip_bfloat16* m    = (__hip_bfloat16*)(wsb + OFF_M);
  float* e   = (float*)(wsb + OFF_E);
  float* inv = (float*)(wsb + OFF_INV);
  void* gip  = (void*)(wsb + OFF_GI);
  const bool gi32 = (ws_size >= NEED_GI32);   // constant across calls -> same work every call

  // k_detect zeroes the h ring (ws is poisoned 0xAA before every call) and sets dflag
  k_detect<<<1, 256, 0, stream>>>((const unsigned short*)d_in[0], dflag, (uint4*)hslots);

  CvtArgs ca;
  float* dsts[11] = {cx, cW0, cb0, cW1, cb1, cW2, cb2, cWih, cWhh, cbi, cbh};
  const int ns[11] = {BB * SS * IN_, IN_ * DD, DD, DD * DA, DA, DA * RR, RR,
                      DD * G3, HH * G3, G3, G3};
  for (int i = 0; i < 11; i++) { ca.src[i] = d_in[i]; ca.dst[i] = dsts[i]; ca.n[i] = ns[i]; }
  k_cvt<<<dim3(128, 11), 256, 0, stream>>>(ca, dflag);

  k_transpose3<<<1600, dim3(32, 32), 0, stream>>>(cWhh, cWih, cW0, WT, WihT, W0T);
  // m = relu(x @ W0 + b0) via MFMA (fp32 A staged to bf16)
  k_gemm<float, __hip_bfloat16, IN_, true>
      <<<dim3(DD / 128, (BB * SS) / 128), 256, 0, stream>>>(cx, W0T, cb0, m, DD);
  k_scores<<<BB * SS, 256, 0, stream>>>(m, cW1, cb1, cW2, cb2, e);
  k_scan<<<BB * RR, 64, 0, stream>>>(e, inv);
  k_attn<<<dim3(4, BB), 128, 0, stream>>>(m, e, inv, Mm);
  if (gi32) {
    k_gemm<__hip_bfloat16, float, DD, false>
        <<<dim3(G3 / 128, (BB * SS) / 128), 256, 0, stream>>>(Mm, WihT, cbi, (float*)gip, G3);
    k_gru<float><<<256, 384, 0, stream>>>(WT, (const float*)gip, cbh, hslots, d_out, dflag);
  } else {
    k_gemm<__hip_bfloat16, __hip_bfloat16, DD, false>
        <<<dim3(G3 / 128, (BB * SS) / 128), 256, 0, stream>>>(Mm, WihT, cbi,
                                                              (__hip_bfloat16*)gip, G3);
    k_gru<__hip_bfloat16><<<256, 384, 0, stream>>>(WT, (const __hip_bfloat16*)gip, cbh,
                                                   hslots, d_out, dflag);
  }
}

// Round 8
// 1031.856 us; speedup vs baseline: 1.3852x; 1.2072x over previous
//
#include <hip/hip_runtime.h>
#include <hip/hip_bf16.h>

// Problem dims
#define BB 16
#define SS 512
#define IN_ 128
#define DD 512
#define HH 512
#define DA 30
#define RR 10
#define G3 1536   // 3*H

// ---- ws layout (bytes) ----
constexpr size_t OFF_H    = 0;                        // tagged h ring u32[2][16][512]: 65,536
constexpr size_t OFF_DF   = 131072;                   // dtype flag: 256
constexpr size_t OFF_CX   = OFF_DF   + 256;           // canonical fp32 inputs
constexpr size_t OFF_CW0  = OFF_CX   + 4194304;
constexpr size_t OFF_CB0  = OFF_CW0  + 262144;
constexpr size_t OFF_CW1  = OFF_CB0  + 2048;
constexpr size_t OFF_CB1  = OFF_CW1  + 61440;
constexpr size_t OFF_CW2  = OFF_CB1  + 256;
constexpr size_t OFF_CB2  = OFF_CW2  + 2048;
constexpr size_t OFF_CWIH = OFF_CB2  + 256;
constexpr size_t OFF_CWHH = OFF_CWIH + 3145728;
constexpr size_t OFF_CBI  = OFF_CWHH + 3145728;
constexpr size_t OFF_CBH  = OFF_CBI  + 6144;
constexpr size_t OFF_WT   = OFF_CBH  + 6144;          // W_hh^T bf16 [1536][512]
constexpr size_t OFF_WIHT = OFF_WT   + 1572864;       // W_ih^T bf16 [1536][512]
constexpr size_t OFF_W0T  = OFF_WIHT + 1572864;       // W0^T bf16 [512][128]
constexpr size_t OFF_MM   = OFF_W0T  + 131072;        // M bf16 [8192][512]
constexpr size_t OFF_BIG  = OFF_MM   + 8388608;
constexpr size_t OFF_M    = OFF_BIG;                  // m bf16 [8192][512]
constexpr size_t OFF_E    = OFF_BIG  + 8388608;       // e f32 [8192][10]
constexpr size_t OFF_INV  = OFF_E    + 327680;        // inv f32
constexpr size_t OFF_GI   = OFF_BIG;                  // gi aliases m/e/inv (dead after k_attn)
constexpr size_t NEED_GI32 = OFF_BIG + 50331648;      // gi fp32 path total

typedef __attribute__((ext_vector_type(8))) short bf16x8;
typedef __attribute__((ext_vector_type(4))) float f32x4;

__device__ __forceinline__ float bflo(unsigned int u) { return __uint_as_float(u << 16); }
__device__ __forceinline__ float bfhi(unsigned int u) { return __uint_as_float(u & 0xffff0000u); }
__device__ __forceinline__ float bf1(unsigned short u) { return __uint_as_float(((unsigned int)u) << 16); }
__device__ __forceinline__ unsigned short f2b(float f) {
  __hip_bfloat16 h = __float2bfloat16(f);
  return *(unsigned short*)&h;
}

__device__ __forceinline__ float ldgi(const float* p) { return *p; }
__device__ __forceinline__ float ldgi(const __hip_bfloat16* p) { return __bfloat162float(*p); }
__device__ __forceinline__ void stgi(float* p, float v) { *p = v; }
__device__ __forceinline__ void stgi(__hip_bfloat16* p, float v) { *p = __float2bfloat16(v); }

// ---------------- K0a: detect input dtype + zero the h ring ----------------
__global__ __launch_bounds__(256) void k_detect(const unsigned short* __restrict__ xs,
                                                int* __restrict__ dflag,
                                                uint4* __restrict__ hz) {
  const int tid = threadIdx.x;
  // zero tagged h ring: 65,536 B = 4096 uint4 (bits 0 == h=0.0 with tag 0)
  const uint4 z = {0u, 0u, 0u, 0u};
  #pragma unroll
  for (int i = 0; i < 16; i++) hz[tid + i * 256] = z;
  int bad = 0;
  for (int i = tid; i < 8192; i += 256) {
    const float v = bf1(xs[i]);
    if (!(fabsf(v) < 1.0e3f)) bad++;   // NaN also counts
  }
  __shared__ int s;
  if (tid == 0) s = 0;
  __syncthreads();
  atomicAdd(&s, bad);
  __syncthreads();
  if (tid == 0) dflag[0] = (s > 16) ? 1 : 0;   // 1 = fp32 buffers, 0 = bf16 buffers
}

// ---------------- K0b: canonicalize all inputs to fp32 ----------------
struct CvtArgs { const void* src[11]; float* dst[11]; int n[11]; };
__global__ __launch_bounds__(256) void k_cvt(CvtArgs a, const int* __restrict__ dflag) {
  const int ai = blockIdx.y;
  const int n = a.n[ai];
  const int stride = gridDim.x * blockDim.x;
  const int f32 = dflag[0];
  float* dst = a.dst[ai];
  if (f32) {
    const float* src = (const float*)a.src[ai];
    for (int i = blockIdx.x * blockDim.x + threadIdx.x; i < n; i += stride) dst[i] = src[i];
  } else {
    const unsigned short* src = (const unsigned short*)a.src[ai];
    for (int i = blockIdx.x * blockDim.x + threadIdx.x; i < n; i += stride) dst[i] = bf1(src[i]);
  }
}

// ---------------- K1: fused transpose of W_hh, W_ih (512x1536) and W0 (128x512) ------
__global__ __launch_bounds__(1024) void k_transpose3(const float* __restrict__ Whh,
    const float* __restrict__ Wih, const float* __restrict__ W0,
    __hip_bfloat16* __restrict__ WhhT, __hip_bfloat16* __restrict__ WihT,
    __hip_bfloat16* __restrict__ W0T) {
  __shared__ float tile[32][33];
  int id = blockIdx.x;
  const float* W; __hip_bfloat16* WT; int R, C, tx, ty;
  if (id < 768)       { W = Whh; WT = WhhT; R = DD;  C = G3; tx = id % 48; ty = id / 48; }
  else if (id < 1536) { id -= 768;  W = Wih; WT = WihT; R = DD;  C = G3; tx = id % 48; ty = id / 48; }
  else                { id -= 1536; W = W0;  WT = W0T;  R = IN_; C = DD; tx = id % 16; ty = id / 16; }
  const int c0 = tx * 32, k0 = ty * 32;
  tile[threadIdx.y][threadIdx.x] = W[(k0 + threadIdx.y) * C + c0 + threadIdx.x];
  __syncthreads();
  WT[(c0 + threadIdx.y) * R + k0 + threadIdx.x] = __float2bfloat16(tile[threadIdx.x][threadIdx.y]);
}

// ---------------- K5: unified MFMA GEMM: C[M][N] = A[M][KD] @ Bt[N][KD]^T + bias ------
// Tile 128x128, 4 waves (2x2 of 64x64), BK=32. A staged fp32->bf16 or bf16 direct.
// C/D frag: col=lane&15, row=quad*4+reg (m89-verified).
template<typename AT, typename GT, int KD, bool RELU>
__global__ __launch_bounds__(256) void k_gemm(const AT* __restrict__ A,
    const __hip_bfloat16* __restrict__ Bt, const float* __restrict__ bias,
    GT* __restrict__ C, int ldc) {
  __shared__ short As[128 * 40];   // 128 rows x 32 k, stride 40 (bank de-phase)
  __shared__ short Bs[128 * 40];
  const int tid = threadIdx.x;
  const int bn = blockIdx.x * 128, bm = blockIdx.y * 128;
  const int lane = tid & 63, w = tid >> 6;
  const int wm = (w >> 1) * 64, wn = (w & 1) * 64;
  const int l15 = lane & 15, quad = lane >> 4;
  const int srow = tid >> 1, shalf = tid & 1;    // staging: row, 16-elem half of 32-chunk
  f32x4 acc[4][4];
  #pragma unroll
  for (int i = 0; i < 4; i++)
    #pragma unroll
    for (int j = 0; j < 4; j++) acc[i][j] = (f32x4){0.f, 0.f, 0.f, 0.f};
  const uint4* Bg = (const uint4*)(Bt + (size_t)(bn + srow) * KD);
  short* Asd = &As[srow * 40 + shalf * 16];
  short* Bsd = &Bs[srow * 40 + shalf * 16];
  #pragma unroll 2
  for (int kc = 0; kc < KD / 32; kc++) {
    if constexpr (sizeof(AT) == 4) {   // fp32 A: 16 floats -> 16 bf16
      const float4* Agf = (const float4*)(A + (size_t)(bm + srow) * KD) + kc * 8 + shalf * 4;
      const float4 f0 = Agf[0], f1 = Agf[1], f2 = Agf[2], f3 = Agf[3];
      unsigned short t16[16] = {
        f2b(f0.x), f2b(f0.y), f2b(f0.z), f2b(f0.w),
        f2b(f1.x), f2b(f1.y), f2b(f1.z), f2b(f1.w),
        f2b(f2.x), f2b(f2.y), f2b(f2.z), f2b(f2.w),
        f2b(f3.x), f2b(f3.y), f2b(f3.z), f2b(f3.w)};
      *(uint4*)&Asd[0] = *(uint4*)&t16[0];
      *(uint4*)&Asd[8] = *(uint4*)&t16[8];
    } else {                            // bf16 A
      const uint4* Ag = (const uint4*)(A + (size_t)(bm + srow) * KD);
      const uint4 a0 = Ag[kc * 4 + shalf * 2], a1 = Ag[kc * 4 + shalf * 2 + 1];
      *(uint4*)&Asd[0] = a0; *(uint4*)&Asd[8] = a1;
    }
    const uint4 b0 = Bg[kc * 4 + shalf * 2], b1 = Bg[kc * 4 + shalf * 2 + 1];
    *(uint4*)&Bsd[0] = b0; *(uint4*)&Bsd[8] = b1;
    __syncthreads();
    bf16x8 af[4], bf[4];
    #pragma unroll
    for (int tt = 0; tt < 4; tt++) {
      af[tt] = *(const bf16x8*)&As[(wm + tt * 16 + l15) * 40 + quad * 8];
      bf[tt] = *(const bf16x8*)&Bs[(wn + tt * 16 + l15) * 40 + quad * 8];
    }
    #pragma unroll
    for (int tm = 0; tm < 4; tm++)
      #pragma unroll
      for (int tn = 0; tn < 4; tn++)
        acc[tm][tn] = __builtin_amdgcn_mfma_f32_16x16x32_bf16(af[tm], bf[tn], acc[tm][tn], 0, 0, 0);
    __syncthreads();
  }
  #pragma unroll
  for (int tn = 0; tn < 4; tn++) {
    const int col = bn + wn + tn * 16 + l15;
    const float bv = bias[col];
    #pragma unroll
    for (int tm = 0; tm < 4; tm++) {
      const int row = bm + wm + tm * 16 + quad * 4;
      #pragma unroll
      for (int i = 0; i < 4; i++) {
        float v = acc[tm][tn][i] + bv;
        if constexpr (RELU) v = fmaxf(v, 0.f);
        stgi(C + (size_t)(row + i) * ldc + col, v);
      }
    }
  }
}

// ---------------- K2b: scores per row: e = exp(tanh(m@W1+b1)@W2+b2) ----------------
__global__ __launch_bounds__(256) void k_scores(const __hip_bfloat16* __restrict__ m,
    const float* __restrict__ W1, const float* __restrict__ b1,
    const float* __restrict__ W2, const float* __restrict__ b2,
    float* __restrict__ e) {
  const int row = blockIdx.x;        // b*512+s
  const int tid = threadIdx.x;       // 256
  __shared__ float ms[DD];
  __shared__ float as[DA];
  __shared__ float part[8][32];
  {
    const unsigned int mm = ((const unsigned int*)(m + (size_t)row * DD))[tid];
    ms[2 * tid] = bflo(mm); ms[2 * tid + 1] = bfhi(mm);
  }
  __syncthreads();
  // m@W1: seg-split over k — all 256 threads active (a2<30 lanes idle only)
  const int a2 = tid & 31, seg = tid >> 5;
  float p = 0.f;
  if (a2 < DA) {
    const int kb = seg * 64;
    #pragma unroll 8
    for (int k = 0; k < 64; k++) p = fmaf(ms[kb + k], W1[(kb + k) * DA + a2], p);
  }
  part[seg][a2] = p;
  __syncthreads();
  if (tid < DA) {
    float a = b1[tid];
    #pragma unroll
    for (int s = 0; s < 8; s++) a += part[s][tid];
    as[tid] = tanhf(a);
  }
  __syncthreads();
  if (tid < RR) {
    float s = b2[tid];
    #pragma unroll
    for (int j = 0; j < DA; j++) s = fmaf(as[j], W2[j * RR + tid], s);
    e[row * RR + tid] = __expf(s);
  }
}

// ---------------- K3: per-(b,r) prefix scan -> inv[b,k,r] = 1/cumsum_k e ----------------
__global__ __launch_bounds__(64) void k_scan(const float* __restrict__ e, float* __restrict__ inv) {
  const int b = blockIdx.x / RR, r = blockIdx.x % RR;
  const int lane = threadIdx.x;  // 64
  float v[8];
  float sum = 0.f;
  #pragma unroll
  for (int i = 0; i < 8; i++) { v[i] = e[(b * SS + lane * 8 + i) * RR + r]; sum += v[i]; }
  float inc = sum;
  #pragma unroll
  for (int off = 1; off < 64; off <<= 1) {
    float n = __shfl_up(inc, off);
    if (lane >= off) inc += n;
  }
  float c = inc - sum;  // exclusive prefix
  #pragma unroll
  for (int i = 0; i < 8; i++) { c += v[i]; inv[(b * SS + lane * 8 + i) * RR + r] = 1.0f / c; }
}

// ---------------- K4: attention as streaming scan: M[t,d] = (1/R) sum_r cums(e*m)*inv ----
__global__ __launch_bounds__(128) void k_attn(const __hip_bfloat16* __restrict__ m,
    const float* __restrict__ e, const float* __restrict__ inv, __hip_bfloat16* __restrict__ M) {
  const int b = blockIdx.y;
  const int d = blockIdx.x * 128 + threadIdx.x;
  __shared__ float es[SS * RR];
  __shared__ float is[SS * RR];
  for (int i = threadIdx.x; i < SS * RR; i += 128) {
    es[i] = e[b * SS * RR + i];
    is[i] = inv[b * SS * RR + i];
  }
  __syncthreads();
  float num[RR];
  #pragma unroll
  for (int r = 0; r < RR; r++) num[r] = 0.f;
  const __hip_bfloat16* mb = m + (size_t)b * SS * DD + d;
  __hip_bfloat16* Mb = M + (size_t)b * SS * DD + d;
  #pragma unroll 4
  for (int k = 0; k < SS; k++) {
    const float mv = __bfloat162float(mb[(size_t)k * DD]);
    float acc = 0.f;
    #pragma unroll
    for (int r = 0; r < RR; r++) {
      num[r] = fmaf(es[k * RR + r], mv, num[r]);
      acc = fmaf(num[r], is[k * RR + r], acc);
    }
    Mb[(size_t)k * DD] = __float2bfloat16(acc * (1.0f / RR));
  }
}

// ---------------- K6 v4 (proven best, rounds 8/10 + this session r0): persistent GRU ----
// 256 blocks x 384 thr, 1 block/CU. Block = (batch b, j-slice g of 32 cols). Swizzle:
// lin = b%8 + 8*(g + 16*(b/8)) -> all 16 blocks of a batch on one XCD (heuristic only).
// W rows (96 x 512) in VGPRs: thread (c<96, q<4) holds 128 bf16 (16 uint4).
// h = u32 fp32-bits with 2-bit mantissa step-tag (tear-proof), parity-2 ring.
// Poll: tid<128, ONE dwordx4 sc0 sc1 per sweep (4 self-tagged dwords). hs4/gis parity
// double-buffered in LDS -> 2 barriers/step. Gates on dedicated wave (tid 352..383) ->
// coalesced h/out stores from a single wave. gi prefetch on tid 256..351.
// SESSION LEDGER (r0-r7): v5 MFMA-batching catastrophic (cross-batch coupling);
// v6 sc0 fast ring INCORRECT (stale clean line + periodic tag = ABA); v7/v9 sc0-only
// spin HANGS (sc0 load never refreshes a stale copy -> polls MUST be sc0 sc1);
// v8 dual-store/pair-ring +12% (extra serial-path traffic); v11 2-deep poll +4%
// (detection quantum NOT in the critical chain). Floor = agent-scope store-visibility
// latency x 512 steps; structural for this 16-CU all-to-all topology.
template<typename GT>
__global__ __launch_bounds__(384) void k_gru(const __hip_bfloat16* __restrict__ WT,
    const GT* __restrict__ gi, const float* __restrict__ bh,
    unsigned int* __restrict__ hslots, void* __restrict__ outv,
    const int* __restrict__ dflag) {
  const int lin = blockIdx.x, tid = threadIdx.x;
  const int xcd = lin & 7, within = lin >> 3;
  const int b = xcd + 8 * (within >> 4);
  const int g = within & 15;                     // j-slice: j in [g*32, g*32+32)
  const int f32o = dflag[0];
  const int c = tid >> 2, q = tid & 3;           // row c<96 (= gate*32+jj), k-quarter q<4
  const int col = ((c >> 5) << 9) + (g << 5) + (c & 31);
  __shared__ __align__(16) float hs4[2][4 * 132];   // parity x 4 padded quarters
  __shared__ float ghs[96];
  __shared__ float gis[2][96];
  // W quarter-row resident in registers: 128 bf16 = 16 uint4 (64 VGPRs)
  uint4 wr[16];
  {
    const uint4* wp = (const uint4*)(WT + (size_t)col * HH + q * 128);
    #pragma unroll
    for (int i = 0; i < 16; i++) wr[i] = wp[i];
  }
  const float bias_c = bh[col];
  // gi prefetch threads: tid in [256,352) <-> slot 0..95
  const int pslot = tid - 256;
  const bool pf = (pslot >= 0 && pslot < 96);
  const int gcol = pf ? (((pslot >> 5) << 9) + (g << 5) + (pslot & 31)) : 0;
  // gates threads: tid in [352,384) <-> jj 0..31
  const bool gt = (tid >= 352);
  const int jj = tid - 352;
  const int jg = (g << 5) + jj;
  unsigned int* s0 = hslots + b * HH;
  unsigned int* s1 = hslots + BB * HH + b * HH;
  const GT* gib = gi + (size_t)b * SS * G3;
  float gpre = pf ? ldgi(gib + gcol) : 0.f;

  for (int t = 0; t < SS; t++) {
    const int par = t & 1;
    unsigned int* cur = par ? s1 : s0;
    unsigned int* nxt = par ? s0 : s1;
    // poll+stage h_t: tid<128 polls one uint4 (slots 4tid..4tid+3, same quarter)
    if (tid < 128) {
      const unsigned want = ((unsigned)t) & 3u;
      const uint4* src = ((const uint4*)cur) + tid;
      uint4 v;
      for (;;) {
        asm volatile("global_load_dwordx4 %0, %1, off sc0 sc1\n\ts_waitcnt vmcnt(0)"
                     : "=v"(v) : "v"(src) : "memory");
        if ((v.x & 3u) == want && (v.y & 3u) == want &&
            (v.z & 3u) == want && (v.w & 3u) == want) break;
      }
      float* dq = &hs4[par][(tid >> 5) * 132 + ((tid * 4) & 127)];
      dq[0] = __uint_as_float(v.x); dq[1] = __uint_as_float(v.y);
      dq[2] = __uint_as_float(v.z); dq[3] = __uint_as_float(v.w);
    }
    if (pf) gis[par][pslot] = gpre;
    __syncthreads();                                    // #1 (stage -> dot)
    if (pf && t + 1 < SS) gpre = ldgi(gib + (size_t)(t + 1) * G3 + gcol);  // overlap dot
    // dot: row col, k in [q*128, q*128+128)
    float a0 = 0.f, a1 = 0.f, a2 = 0.f, a3 = 0.f;
    const float4* hp = (const float4*)&hs4[par][q * 132];
    #pragma unroll
    for (int i = 0; i < 16; i++) {
      const uint4 w = wr[i];
      const float4 ha = hp[2 * i];
      const float4 hb = hp[2 * i + 1];
      a0 = fmaf(ha.x, bflo(w.x), a0); a1 = fmaf(ha.y, bfhi(w.x), a1);
      a2 = fmaf(ha.z, bflo(w.y), a2); a3 = fmaf(ha.w, bfhi(w.y), a3);
      a0 = fmaf(hb.x, bflo(w.z), a0); a1 = fmaf(hb.y, bfhi(w.z), a1);
      a2 = fmaf(hb.z, bflo(w.w), a2); a3 = fmaf(hb.w, bfhi(w.w), a3);
    }
    float acc = (a0 + a1) + (a2 + a3);
    acc += __shfl_xor(acc, 1);   // reduce across q (lane bits 0..1)
    acc += __shfl_xor(acc, 2);
    if (q == 0) ghs[c] = acc + bias_c;
    __syncthreads();                                    // #2 (ghs/gis -> gates; hs4 WAR)
    if (gt) {
      const float ghr = ghs[jj], ghz = ghs[32 + jj], ghn = ghs[64 + jj];
      const float gir = gis[par][jj], giz = gis[par][32 + jj], gin = gis[par][64 + jj];
      const float r = 1.f / (1.f + __expf(-(gir + ghr)));
      const float z = 1.f / (1.f + __expf(-(giz + ghz)));
      const float nx = gin + r * ghn;
      const float n = 1.f - 2.f / (__expf(2.f * nx) + 1.f);   // tanh
      const float hprev = hs4[par][(jg >> 7) * 132 + (jg & 127)];
      const float hnew = n + z * (hprev - n);
      const unsigned pk = (__float_as_uint(hnew) & ~3u) | (((unsigned)(t + 1)) & 3u);
      __hip_atomic_store(nxt + jg, pk, __ATOMIC_RELAXED, __HIP_MEMORY_SCOPE_AGENT);
      const size_t oi = ((size_t)b * SS + t) * HH + jg;
      if (f32o) ((float*)outv)[oi] = hnew;
      else ((__hip_bfloat16*)outv)[oi] = __float2bfloat16(hnew);
    }
    // no barrier #3: hs4/gis parity double-buffered; ghs WAR fenced by barrier #1
  }
}

extern "C" void kernel_launch(void* const* d_in, const int* in_sizes, int n_in,
                              void* d_out, int out_size, void* d_ws, size_t ws_size,
                              hipStream_t stream) {
  char* wsb = (char*)d_ws;
  unsigned int* hslots = (unsigned int*)(wsb + OFF_H);
  int* dflag  = (int*)(wsb + OFF_DF);
  float* cx   = (float*)(wsb + OFF_CX);
  float* cW0  = (float*)(wsb + OFF_CW0);
  float* cb0  = (float*)(wsb + OFF_CB0);
  float* cW1  = (float*)(wsb + OFF_CW1);
  float* cb1  = (float*)(wsb + OFF_CB1);
  float* cW2  = (float*)(wsb + OFF_CW2);
  float* cb2  = (float*)(wsb + OFF_CB2);
  float* cWih = (float*)(wsb + OFF_CWIH);
  float* cWhh = (float*)(wsb + OFF_CWHH);
  float* cbi  = (float*)(wsb + OFF_CBI);
  float* cbh  = (float*)(wsb + OFF_CBH);
  __hip_bfloat16* WT   = (__hip_bfloat16*)(wsb + OFF_WT);
  __hip_bfloat16* WihT = (__hip_bfloat16*)(wsb + OFF_WIHT);
  __hip_bfloat16* W0T  = (__hip_bfloat16*)(wsb + OFF_W0T);
  __hip_bfloat16* Mm   = (__hip_bfloat16*)(wsb + OFF_MM);
  __hip_bfloat16* m    = (__hip_bfloat16*)(wsb + OFF_M);
  float* e   = (float*)(wsb + OFF_E);
  float* inv = (float*)(wsb + OFF_INV);
  void* gip  = (void*)(wsb + OFF_GI);
  const bool gi32 = (ws_size >= NEED_GI32);   // constant across calls -> same work every call

  // k_detect zeroes the h ring (ws is poisoned 0xAA before every call) and sets dflag
  k_detect<<<1, 256, 0, stream>>>((const unsigned short*)d_in[0], dflag, (uint4*)hslots);

  CvtArgs ca;
  float* dsts[11] = {cx, cW0, cb0, cW1, cb1, cW2, cb2, cWih, cWhh, cbi, cbh};
  const int ns[11] = {BB * SS * IN_, IN_ * DD, DD, DD * DA, DA, DA * RR, RR,
                      DD * G3, HH * G3, G3, G3};
  for (int i = 0; i < 11; i++) { ca.src[i] = d_in[i]; ca.dst[i] = dsts[i]; ca.n[i] = ns[i]; }
  k_cvt<<<dim3(128, 11), 256, 0, stream>>>(ca, dflag);

  k_transpose3<<<1600, dim3(32, 32), 0, stream>>>(cWhh, cWih, cW0, WT, WihT, W0T);
  // m = relu(x @ W0 + b0) via MFMA (fp32 A staged to bf16)
  k_gemm<float, __hip_bfloat16, IN_, true>
      <<<dim3(DD / 128, (BB * SS) / 128), 256, 0, stream>>>(cx, W0T, cb0, m, DD);
  k_scores<<<BB * SS, 256, 0, stream>>>(m, cW1, cb1, cW2, cb2, e);
  k_scan<<<BB * RR, 64, 0, stream>>>(e, inv);
  k_attn<<<dim3(4, BB), 128, 0, stream>>>(m, e, inv, Mm);
  if (gi32) {
    k_gemm<__hip_bfloat16, float, DD, false>
        <<<dim3(G3 / 128, (BB * SS) / 128), 256, 0, stream>>>(Mm, WihT, cbi, (float*)gip, G3);
    k_gru<float><<<256, 384, 0, stream>>>(WT, (const float*)gip, cbh, hslots, d_out, dflag);
  } else {
    k_gemm<__hip_bfloat16, __hip_bfloat16, DD, false>
        <<<dim3(G3 / 128, (BB * SS) / 128), 256, 0, stream>>>(Mm, WihT, cbi,
                                                              (__hip_bfloat16*)gip, G3);
    k_gru<__hip_bfloat16><<<256, 384, 0, stream>>>(WT, (const __hip_bfloat16*)gip, cbh,
                                                   hslots, d_out, dflag);
  }
}